// Round 5
// baseline (858.358 us; speedup 1.0000x reference)
//
#include <hip/hip_runtime.h>

#define N_NODES 50000
#define N_EDGES 800000
#define NPAD 50176   // 196*256

typedef __attribute__((ext_vector_type(8))) short short8v;   // 8 bf16 (4 VGPR)
typedef __attribute__((ext_vector_type(4))) float f32x4;

union U4S8 { uint4 u; short8v s; };
__device__ __forceinline__ short8v as_frag(uint4 u) { U4S8 t; t.u = u; return t.s; }
__device__ __forceinline__ uint4 zero4() { return make_uint4(0u, 0u, 0u, 0u); }

// ---------------- degree / CSR build ----------------

__global__ __launch_bounds__(256) void k_deg_i(const int* __restrict__ dst, int* __restrict__ degi) {
    int e = blockIdx.x * 256 + threadIdx.x;
    if (e < N_EDGES) atomicAdd(&degi[dst[e]], 1);
}

// block-level exclusive scan of degi + dinv computation
__global__ __launch_bounds__(256) void k_scan1(const int* __restrict__ degi, int* __restrict__ part,
                                               int* __restrict__ bsum, float* __restrict__ dinv) {
    __shared__ int tmp[256];
    int t = threadIdx.x, gid = blockIdx.x * 256 + t;
    int v = degi[gid];
    if (gid < N_NODES) dinv[gid] = rsqrtf((float)v + 1.0f);
    tmp[t] = v;
    __syncthreads();
    for (int off = 1; off < 256; off <<= 1) {
        int add = (t >= off) ? tmp[t - off] : 0;
        __syncthreads();
        tmp[t] += add;
        __syncthreads();
    }
    part[gid] = tmp[t] - v;
    if (t == 255) bsum[blockIdx.x] = tmp[t];
}

__global__ __launch_bounds__(256) void k_scan2(int* __restrict__ bsum) {
    __shared__ int tmp[256];
    int t = threadIdx.x;
    int v = (t < 196) ? bsum[t] : 0;
    tmp[t] = v;
    __syncthreads();
    for (int off = 1; off < 256; off <<= 1) {
        int add = (t >= off) ? tmp[t - off] : 0;
        __syncthreads();
        tmp[t] += add;
        __syncthreads();
    }
    if (t < 196) bsum[t] = tmp[t] - v;
}

__global__ __launch_bounds__(256) void k_scan3(const int* __restrict__ part, const int* __restrict__ bsum,
                                               int* __restrict__ rowp) {
    int gid = blockIdx.x * 256 + threadIdx.x;
    rowp[gid] = part[gid] + bsum[blockIdx.x];
}

// bucket-place edges into CSR; en = dinv[src]*dinv[dst] computed inline
__global__ __launch_bounds__(256) void k_place(const int* __restrict__ src, const int* __restrict__ dst,
                                               const float* __restrict__ dinv, const int* __restrict__ rowp,
                                               int* __restrict__ cur, int* __restrict__ es, float* __restrict__ en) {
    int e = blockIdx.x * 256 + threadIdx.x;
    if (e >= N_EDGES) return;
    int s = src[e], d = dst[e];
    int p = atomicAdd(&cur[d], 1);
    int slot = rowp[d] + p;
    es[slot] = s;
    en[slot] = dinv[s] * dinv[d];
}

// ---------------- weight / bias pre-pack ----------------
// s 0..13 (edge pipeline, TRANSPOSED A-operand layout):
//   uint4 offset = s*1024 + ((t_tile*2+kt)*2+h)*64 + lane ; h=0 hi, h=1 lo
//   value(lane, i): A[m][k] = W_s[fi][fo], fo = 16*t_tile + (lane&15), fi = 32*kt + 8*(lane>>4) + i
// s 14..17 (gcn, B-operand layout as R4): [s][kt][nt][lane][8u32]

__global__ __launch_bounds__(256) void k_wprep(const float* __restrict__ ew0, const float* __restrict__ ew,
                                               const float* __restrict__ ow0, const float* __restrict__ ow,
                                               const float* __restrict__ gw, unsigned* __restrict__ wpk) {
    int t = blockIdx.x * 256 + threadIdx.x;
    if (t >= 18 * 512) return;
    int lane = t & 63;
    int s = t >> 9;
    unsigned hu[8], lu[8];
    if (s < 14) {
        int q = (t >> 6) & 7;
        int tt = q >> 1, kt = q & 1;
        int fo = 16 * tt + (lane & 15);
#pragma unroll
        for (int i = 0; i < 8; ++i) {
            int fi = 32 * kt + 8 * (lane >> 4) + i;
            float w = 0.f;
            if (s == 0)       { if (fi < 16) w = ew0[fi * 64 + fo]; }
            else if (s <= 7)  w = ew[((s - 1) * 64 + fi) * 64 + fo];
            else if (s == 8)  w = ow0[(128 + fi) * 64 + fo];
            else if (s == 9)  w = ow0[fi * 64 + fo];
            else if (s == 10) w = ow0[(64 + fi) * 64 + fo];
            else              w = ow[((s - 11) * 64 + fi) * 64 + fo];
            unsigned u = __float_as_uint(w);
            unsigned h = u & 0xFFFF0000u;
            float d = w - __uint_as_float(h);
            hu[i] = h >> 16;
            lu[i] = __float_as_uint(d) >> 16;
        }
        uint4* o = (uint4*)wpk + (size_t)s * 1024 + ((tt * 2 + kt) * 2) * 64 + lane;
        o[0]  = make_uint4(hu[0] | (hu[1] << 16), hu[2] | (hu[3] << 16), hu[4] | (hu[5] << 16), hu[6] | (hu[7] << 16));
        o[64] = make_uint4(lu[0] | (lu[1] << 16), lu[2] | (lu[3] << 16), lu[4] | (lu[5] << 16), lu[6] | (lu[7] << 16));
    } else {
        int nt = (t >> 6) & 3;
        int kt = (t >> 8) & 1;
        int n = nt * 16 + (lane & 15);
#pragma unroll
        for (int i = 0; i < 8; ++i) {
            int k = kt * 32 + ((lane >> 4) * 8) + i;
            float w = gw[((s - 14) * 64 + k) * 64 + n];
            unsigned u = __float_as_uint(w);
            unsigned h = u & 0xFFFF0000u;
            float d = w - __uint_as_float(h);
            hu[i] = h >> 16;
            lu[i] = __float_as_uint(d) >> 16;
        }
        uint4* o = (uint4*)(wpk + (size_t)t * 8);
        o[0] = make_uint4(hu[0] | (hu[1] << 16), hu[2] | (hu[3] << 16), hu[4] | (hu[5] << 16), hu[6] | (hu[7] << 16));
        o[1] = make_uint4(lu[0] | (lu[1] << 16), lu[2] | (lu[3] << 16), lu[4] | (lu[5] << 16), lu[6] | (lu[7] << 16));
    }
}

// biasArr2: s*64 + idx, idx = g*16 + t*4 + r  <->  feat f = 16t + 4g + r
// slot 14 = fin_w (same pattern), biasArr2[15*64] = fin_b
__global__ __launch_bounds__(256) void k_bprep(const float* __restrict__ eb0, const float* __restrict__ eb,
                                               const float* __restrict__ ob0, const float* __restrict__ ob,
                                               const float* __restrict__ finw, const float* __restrict__ finb,
                                               float* __restrict__ biasArr2) {
    int t = blockIdx.x * 256 + threadIdx.x;
    if (t > 15 * 64) return;
    if (t == 15 * 64) { biasArr2[t] = finb[0]; return; }
    int s = t >> 6, idx = t & 63;
    int f = 16 * ((idx >> 2) & 3) + 4 * (idx >> 4) + (idx & 3);
    float b = 0.f;
    if (s == 0) b = eb0[f];
    else if (s <= 7) b = eb[(s - 1) * 64 + f];
    else if (s == 8) b = ob0[f];
    else if (s >= 11 && s <= 13) b = ob[(s - 11) * 64 + f];
    else if (s == 14) b = finw[f];
    biasArr2[t] = b;
}

// ---------------- shared split helpers ----------------

__device__ __forceinline__ void split_pack8(const float* xv, uint4& hfrag, uint4& lfrag) {
    unsigned hu[8], lu[8];
#pragma unroll
    for (int i = 0; i < 8; ++i) {
        unsigned u = __float_as_uint(xv[i]);
        unsigned h = u & 0xFFFF0000u;
        float d = xv[i] - __uint_as_float(h);
        hu[i] = h >> 16;
        lu[i] = __float_as_uint(d) >> 16;
    }
    hfrag = make_uint4(hu[0] | (hu[1] << 16), hu[2] | (hu[3] << 16), hu[4] | (hu[5] << 16), hu[6] | (hu[7] << 16));
    lfrag = make_uint4(lu[0] | (lu[1] << 16), lu[2] | (lu[3] << 16), lu[4] | (lu[5] << 16), lu[6] | (lu[7] << 16));
}

__device__ __forceinline__ void load_a_global_kt(const float* rowp, int kt, int g, uint4& aH, uint4& aL) {
    const float4* r4 = (const float4*)(rowp + kt * 32 + g * 8);
    float4 f0 = r4[0], f1 = r4[1];
    float xv[8] = {f0.x, f0.y, f0.z, f0.w, f1.x, f1.y, f1.z, f1.w};
    split_pack8(xv, aH, aL);
}

// B-operand-style mfma (gcn stages): acc[2][4], weights [kt][nt][lane]
__device__ __forceinline__ void mfma_stage(f32x4 acc[2][4], const uint4* wqs,
                                           const uint4 aH[2][2], const uint4 aL[2][2], int lane) {
#pragma unroll
    for (int kt = 0; kt < 2; ++kt) {
#pragma unroll
        for (int nt = 0; nt < 4; ++nt) {
            const uint4* wq = wqs + ((size_t)((kt * 4 + nt) * 64 + lane)) * 2;
            short8v bh = as_frag(wq[0]);
            short8v bl = as_frag(wq[1]);
#pragma unroll
            for (int mt = 0; mt < 2; ++mt) {
                short8v ah = as_frag(aH[mt][kt]);
                short8v al = as_frag(aL[mt][kt]);
                acc[mt][nt] = __builtin_amdgcn_mfma_f32_16x16x32_bf16(ah, bh, acc[mt][nt], 0, 0, 0);
                acc[mt][nt] = __builtin_amdgcn_mfma_f32_16x16x32_bf16(al, bh, acc[mt][nt], 0, 0, 0);
                acc[mt][nt] = __builtin_amdgcn_mfma_f32_16x16x32_bf16(ah, bl, acc[mt][nt], 0, 0, 0);
            }
        }
    }
}

// ---------------- GCN node GEMM (unchanged structure from R4) ----------------

__global__ __launch_bounds__(256, 3) void k_xlm(const float* __restrict__ xin,
                                                const unsigned* __restrict__ wpk, int stage,
                                                float* __restrict__ xl) {
    const int tid = threadIdx.x;
    const int wv = tid >> 6, lane = tid & 63;
    const int g = lane >> 4, l15 = lane & 15;
    const int rb = blockIdx.x * 128 + wv * 32;
    const uint4* wq = (const uint4*)wpk + (size_t)stage * 1024;

    f32x4 acc[2][4];
    uint4 aH[2][2], aL[2][2];
#pragma unroll
    for (int mt = 0; mt < 2; ++mt) {
        int row = rb + mt * 16 + l15;
        if (row < N_NODES) {
            const float* rowp = xin + (size_t)row * 64;
#pragma unroll
            for (int kt = 0; kt < 2; ++kt) load_a_global_kt(rowp, kt, g, aH[mt][kt], aL[mt][kt]);
        } else {
#pragma unroll
            for (int kt = 0; kt < 2; ++kt) { aH[mt][kt] = zero4(); aL[mt][kt] = zero4(); }
        }
#pragma unroll
        for (int nt = 0; nt < 4; ++nt) acc[mt][nt] = (f32x4){0.f, 0.f, 0.f, 0.f};
    }
    mfma_stage(acc, wq, aH, aL, lane);
#pragma unroll
    for (int mt = 0; mt < 2; ++mt)
#pragma unroll
        for (int nt = 0; nt < 4; ++nt)
#pragma unroll
            for (int r = 0; r < 4; ++r) {
                int row = rb + mt * 16 + g * 4 + r;
                if (row < N_NODES) xl[(size_t)row * 64 + nt * 16 + l15] = acc[mt][nt][r];
            }
}

// ---------------- segmented aggregation (+ optional split output) ----------------

__global__ __launch_bounds__(256) void k_agg(const float* __restrict__ xl,
                                             const int* __restrict__ es, const float* __restrict__ en,
                                             const int* __restrict__ rowp, const float* __restrict__ dinv,
                                             const float* __restrict__ b, float* __restrict__ xout,
                                             unsigned short* __restrict__ oh, unsigned short* __restrict__ ol,
                                             int writeSplit) {
    int n = blockIdx.x * 4 + (threadIdx.x >> 6);
    int j = threadIdx.x & 63;
    if (n >= N_NODES) return;
    int i = rowp[n], e1 = rowp[n + 1];
    float a0 = 0.f, a1 = 0.f;
    for (; i + 1 < e1; i += 2) {
        int s0 = es[i], s1 = es[i + 1];
        float w0 = en[i], w1 = en[i + 1];
        a0 = fmaf(w0, xl[(size_t)s0 * 64 + j], a0);
        a1 = fmaf(w1, xl[(size_t)s1 * 64 + j], a1);
    }
    if (i < e1) a0 = fmaf(en[i], xl[(size_t)es[i] * 64 + j], a0);
    float di = dinv[n];
    float val = a0 + a1 + di * di * xl[(size_t)n * 64 + j] + b[j];
    float v = fmaxf(val, 0.f);
    size_t idx = (size_t)n * 64 + j;
    xout[idx] = v;
    if (writeSplit) {
        unsigned u = __float_as_uint(v);
        oh[idx] = (unsigned short)(u >> 16);
        float d = v - __uint_as_float(u & 0xFFFF0000u);
        ol[idx] = (unsigned short)(__float_as_uint(d) >> 16);
    }
}

// ---------------- fused edge mega kernel v2: register-resident swapped-operand ----------------
// wave = 16 edges (c = lane&15); P = act^T kept in acc/C-D layout; no LDS storage, no barriers.

__device__ __forceinline__ void bias_init(f32x4 acc[4], const float* bp) {
    const float4* b4 = (const float4*)bp;
#pragma unroll
    for (int t = 0; t < 4; ++t) {
        float4 b = b4[t];
        acc[t] = (f32x4){b.x, b.y, b.z, b.w};
    }
}

// relu + split + in-wave transpose: acc (C/D layout) -> B-frags for next stage
__device__ __forceinline__ void exchange(const f32x4 acc[4], unsigned BH[2][4], unsigned BL[2][4],
                                         int bp01, int bp23, bool ghi) {
    unsigned pkH[4][2], pkL[4][2];
#pragma unroll
    for (int t = 0; t < 4; ++t) {
#pragma unroll
        for (int j = 0; j < 2; ++j) {
            float a0 = fmaxf(acc[t][2 * j], 0.f), a1 = fmaxf(acc[t][2 * j + 1], 0.f);
            unsigned ph;
            asm("v_cvt_pk_bf16_f32 %0, %1, %2" : "=v"(ph) : "v"(a0), "v"(a1));
            float d0 = a0 - __uint_as_float(ph << 16);
            float d1 = a1 - __uint_as_float(ph & 0xFFFF0000u);
            unsigned pl;
            asm("v_cvt_pk_bf16_f32 %0, %1, %2" : "=v"(pl) : "v"(d0), "v"(d1));
            pkH[t][j] = ph;
            pkL[t][j] = pl;
        }
    }
#pragma unroll
    for (int kt = 0; kt < 2; ++kt) {
#pragma unroll
        for (int w = 0; w < 4; ++w) {
            int idx = (w < 2) ? bp01 : bp23;
            unsigned h0 = (unsigned)__builtin_amdgcn_ds_bpermute(idx, (int)pkH[2 * kt][w & 1]);
            unsigned h1 = (unsigned)__builtin_amdgcn_ds_bpermute(idx, (int)pkH[2 * kt + 1][w & 1]);
            BH[kt][w] = ghi ? h1 : h0;
            unsigned l0 = (unsigned)__builtin_amdgcn_ds_bpermute(idx, (int)pkL[2 * kt][w & 1]);
            unsigned l1 = (unsigned)__builtin_amdgcn_ds_bpermute(idx, (int)pkL[2 * kt + 1][w & 1]);
            BL[kt][w] = ghi ? l1 : l0;
        }
    }
}

template <int KTMAX>
__device__ __forceinline__ void mfma_T(f32x4 acc[4], const uint4* wq,
                                       const unsigned BH[2][4], const unsigned BL[2][4], int lane) {
#pragma unroll
    for (int kt = 0; kt < KTMAX; ++kt) {
        short8v Bh = as_frag(make_uint4(BH[kt][0], BH[kt][1], BH[kt][2], BH[kt][3]));
        short8v Bl = as_frag(make_uint4(BL[kt][0], BL[kt][1], BL[kt][2], BL[kt][3]));
#pragma unroll
        for (int t = 0; t < 4; ++t) {
            short8v Ah = as_frag(wq[((t * 2 + kt) * 2 + 0) * 64 + lane]);
            short8v Al = as_frag(wq[((t * 2 + kt) * 2 + 1) * 64 + lane]);
            acc[t] = __builtin_amdgcn_mfma_f32_16x16x32_bf16(Ah, Bh, acc[t], 0, 0, 0);
            acc[t] = __builtin_amdgcn_mfma_f32_16x16x32_bf16(Al, Bh, acc[t], 0, 0, 0);
            acc[t] = __builtin_amdgcn_mfma_f32_16x16x32_bf16(Ah, Bl, acc[t], 0, 0, 0);
        }
    }
}

__device__ __forceinline__ void loadB_split(const unsigned short* xhi, const unsigned short* xlo,
                                            int node, int g, unsigned BH[2][4], unsigned BL[2][4]) {
    const uint4* hp = (const uint4*)xhi + (size_t)node * 8;
    const uint4* lp = (const uint4*)xlo + (size_t)node * 8;
#pragma unroll
    for (int kt = 0; kt < 2; ++kt) {
        uint4 h4 = hp[kt * 4 + g];
        BH[kt][0] = h4.x; BH[kt][1] = h4.y; BH[kt][2] = h4.z; BH[kt][3] = h4.w;
        uint4 l4 = lp[kt * 4 + g];
        BL[kt][0] = l4.x; BL[kt][1] = l4.y; BL[kt][2] = l4.z; BL[kt][3] = l4.w;
    }
}

__global__ __launch_bounds__(256, 3) void k_mega(
    const float* __restrict__ ea, const int* __restrict__ src, const int* __restrict__ dst,
    const unsigned short* __restrict__ xhi, const unsigned short* __restrict__ xlo,
    const unsigned* __restrict__ wpk, const float* __restrict__ biasArr2,
    float* __restrict__ out) {
    const int tid = threadIdx.x;
    const int wv = tid >> 6, lane = tid & 63;
    const int g = lane >> 4, c = lane & 15;
    const int ebase = blockIdx.x * 64 + wv * 16;
    const bool ghi = (g >= 2);
    const int bp01 = (((g & 1) << 5) | c) << 2;
    const int bp23 = bp01 + 64;
    const uint4* wpk4 = (const uint4*)wpk;

    f32x4 acc[4];
    unsigned BH[2][4], BL[2][4];

    // ---- s0: B from edge_attr (K=16, kt=0 only) ----
    if (g < 2) {
        const float4* ar = (const float4*)(ea + (size_t)(ebase + c) * 16 + 8 * g);
        float4 f0 = ar[0], f1 = ar[1];
        float xv[8] = {f0.x, f0.y, f0.z, f0.w, f1.x, f1.y, f1.z, f1.w};
        uint4 hf, lf;
        split_pack8(xv, hf, lf);
        BH[0][0] = hf.x; BH[0][1] = hf.y; BH[0][2] = hf.z; BH[0][3] = hf.w;
        BL[0][0] = lf.x; BL[0][1] = lf.y; BL[0][2] = lf.z; BL[0][3] = lf.w;
    } else {
#pragma unroll
        for (int w = 0; w < 4; ++w) { BH[0][w] = 0u; BL[0][w] = 0u; }
    }
    bias_init(acc, biasArr2 + g * 16);
    mfma_T<1>(acc, wpk4, BH, BL, lane);

    // ---- s1..s7: edge MLP ----
    for (int s = 1; s <= 7; ++s) {
        exchange(acc, BH, BL, bp01, bp23, ghi);
        bias_init(acc, biasArr2 + s * 64 + g * 16);
        mfma_T<2>(acc, wpk4 + (size_t)s * 1024, BH, BL, lane);
    }

    // ---- s8: e-chunk of out_w0 (bias ob0) ----
    exchange(acc, BH, BL, bp01, bp23, ghi);
    bias_init(acc, biasArr2 + 8 * 64 + g * 16);
    mfma_T<2>(acc, wpk4 + (size_t)8 * 1024, BH, BL, lane);

    // ---- s9: + x[src]; s10: + x[dst] (accumulate) ----
    {
        int node = src[ebase + c];
        loadB_split(xhi, xlo, node, g, BH, BL);
        mfma_T<2>(acc, wpk4 + (size_t)9 * 1024, BH, BL, lane);
        node = dst[ebase + c];
        loadB_split(xhi, xlo, node, g, BH, BL);
        mfma_T<2>(acc, wpk4 + (size_t)10 * 1024, BH, BL, lane);
    }

    // ---- s11..s13: out MLP ----
    for (int s = 11; s <= 13; ++s) {
        exchange(acc, BH, BL, bp01, bp23, ghi);
        bias_init(acc, biasArr2 + s * 64 + g * 16);
        mfma_T<2>(acc, wpk4 + (size_t)s * 1024, BH, BL, lane);
    }

    // ---- final dot: out = relu(P14)^T . fin_w + fin_b ----
    const float4* fw4 = (const float4*)(biasArr2 + 14 * 64 + g * 16);
    const float fb = biasArr2[15 * 64];
    float v = 0.f;
#pragma unroll
    for (int t = 0; t < 4; ++t) {
        float4 w4 = fw4[t];
        v = fmaf(fmaxf(acc[t][0], 0.f), w4.x, v);
        v = fmaf(fmaxf(acc[t][1], 0.f), w4.y, v);
        v = fmaf(fmaxf(acc[t][2], 0.f), w4.z, v);
        v = fmaf(fmaxf(acc[t][3], 0.f), w4.w, v);
    }
    v += __shfl_xor(v, 16, 64);
    v += __shfl_xor(v, 32, 64);
    if (lane < 16) out[ebase + c] = v + fb;
}

// ---------------- launch ----------------

extern "C" void kernel_launch(void* const* d_in, const int* in_sizes, int n_in,
                              void* d_out, int out_size, void* d_ws, size_t ws_size,
                              hipStream_t stream) {
    (void)in_sizes; (void)n_in; (void)out_size; (void)ws_size;

    const float* x         = (const float*)d_in[0];
    const int*   src       = (const int*)d_in[1];
    const int*   dst       = (const int*)d_in[2];
    const float* edge_attr = (const float*)d_in[3];
    const float* gcn_w     = (const float*)d_in[4];
    const float* gcn_b     = (const float*)d_in[5];
    const float* edge_w0   = (const float*)d_in[6];
    const float* edge_b0   = (const float*)d_in[7];
    const float* edge_w    = (const float*)d_in[8];
    const float* edge_b    = (const float*)d_in[9];
    const float* out_w0    = (const float*)d_in[10];
    const float* out_b0    = (const float*)d_in[11];
    const float* out_w     = (const float*)d_in[12];
    const float* out_b     = (const float*)d_in[13];
    const float* fin_w     = (const float*)d_in[14];
    const float* fin_b     = (const float*)d_in[15];
    float* out = (float*)d_out;

    float* ws    = (float*)d_ws;
    float* dinv  = ws;                                  // NPAD
    float* xbufA = dinv + NPAD;                         // N*64
    float* xl    = xbufA + N_NODES * 64;                // N*64
    unsigned short* xhi = (unsigned short*)(xl + N_NODES * 64);   // N*64 u16
    unsigned short* xlo = xhi + N_NODES * 64;                     // N*64 u16
    float* scr   = (float*)(xlo + N_NODES * 64);
    unsigned* wpk   = (unsigned*)scr;                   // 18*4096 = 73728 u32
    float* biasArr2 = scr + 73728;                      // 1088
    int* degi       = (int*)(scr + 74816);              // NPAD
    int* cur        = degi + NPAD;                      // NPAD (adjacent for one memset)
    int* part       = cur + NPAD;                       // NPAD
    int* bsum       = part + NPAD;                      // 256
    int* rowp       = bsum + 256;                       // NPAD
    int* es         = rowp + NPAD;                      // E
    float* en       = (float*)(es + N_EDGES);           // E

    const int EB = N_EDGES / 256;                       // 3125
    const int NB = NPAD / 256;                          // 196

    hipMemsetAsync(degi, 0, 2 * NPAD * sizeof(int), stream);
    k_deg_i<<<EB, 256, 0, stream>>>(dst, degi);
    k_scan1<<<NB, 256, 0, stream>>>(degi, part, bsum, dinv);
    k_scan2<<<1, 256, 0, stream>>>(bsum);
    k_scan3<<<NB, 256, 0, stream>>>(part, bsum, rowp);
    k_place<<<EB, 256, 0, stream>>>(src, dst, dinv, rowp, cur, es, en);

    k_wprep<<<36, 256, 0, stream>>>(edge_w0, edge_w, out_w0, out_w, gcn_w, wpk);
    k_bprep<<<4, 256, 0, stream>>>(edge_b0, edge_b, out_b0, out_b, fin_w, fin_b, biasArr2);

    const float* xin = x;
    for (int layer = 0; layer < 4; ++layer) {
        k_xlm<<<(NPAD / 128), 256, 0, stream>>>(xin, wpk, 14 + layer, xl);
        k_agg<<<(N_NODES + 3) / 4, 256, 0, stream>>>(xl, es, en, rowp, dinv,
                                                     gcn_b + layer * 64, xbufA,
                                                     xhi, xlo, (layer == 3) ? 1 : 0);
        xin = xbufA;
    }

    k_mega<<<N_EDGES / 64, 256, 0, stream>>>(edge_attr, src, dst, xhi, xlo,
                                             wpk, biasArr2, out);
}

// Round 6
// 606.793 us; speedup vs baseline: 1.4146x; 1.4146x over previous
//
#include <hip/hip_runtime.h>

#define N_NODES 50000
#define N_EDGES 800000
#define NPAD 50176   // 196*256

typedef __attribute__((ext_vector_type(8))) short short8v;   // 8 bf16 (4 VGPR)
typedef __attribute__((ext_vector_type(4))) float f32x4;
typedef __attribute__((ext_vector_type(16))) float f32x16;
typedef __attribute__((ext_vector_type(2))) unsigned uint2v;

union U4S8 { uint4 u; short8v s; };
__device__ __forceinline__ short8v as_frag(uint4 u) { U4S8 t; t.u = u; return t.s; }
__device__ __forceinline__ uint4 zero4() { return make_uint4(0u, 0u, 0u, 0u); }

// ---------------- degree / CSR build ----------------

__global__ __launch_bounds__(256) void k_deg_i(const int* __restrict__ dst, int* __restrict__ degi) {
    int e = blockIdx.x * 256 + threadIdx.x;
    if (e < N_EDGES) atomicAdd(&degi[dst[e]], 1);
}

__global__ __launch_bounds__(256) void k_scan1(const int* __restrict__ degi, int* __restrict__ part,
                                               int* __restrict__ bsum, float* __restrict__ dinv) {
    __shared__ int tmp[256];
    int t = threadIdx.x, gid = blockIdx.x * 256 + t;
    int v = degi[gid];
    if (gid < N_NODES) dinv[gid] = rsqrtf((float)v + 1.0f);
    tmp[t] = v;
    __syncthreads();
    for (int off = 1; off < 256; off <<= 1) {
        int add = (t >= off) ? tmp[t - off] : 0;
        __syncthreads();
        tmp[t] += add;
        __syncthreads();
    }
    part[gid] = tmp[t] - v;
    if (t == 255) bsum[blockIdx.x] = tmp[t];
}

__global__ __launch_bounds__(256) void k_scan2(int* __restrict__ bsum) {
    __shared__ int tmp[256];
    int t = threadIdx.x;
    int v = (t < 196) ? bsum[t] : 0;
    tmp[t] = v;
    __syncthreads();
    for (int off = 1; off < 256; off <<= 1) {
        int add = (t >= off) ? tmp[t - off] : 0;
        __syncthreads();
        tmp[t] += add;
        __syncthreads();
    }
    if (t < 196) bsum[t] = tmp[t] - v;
}

__global__ __launch_bounds__(256) void k_scan3(const int* __restrict__ part, const int* __restrict__ bsum,
                                               int* __restrict__ rowp) {
    int gid = blockIdx.x * 256 + threadIdx.x;
    rowp[gid] = part[gid] + bsum[blockIdx.x];
}

__global__ __launch_bounds__(256) void k_place(const int* __restrict__ src, const int* __restrict__ dst,
                                               const float* __restrict__ dinv, const int* __restrict__ rowp,
                                               int* __restrict__ cur, int* __restrict__ es, float* __restrict__ en) {
    int e = blockIdx.x * 256 + threadIdx.x;
    if (e >= N_EDGES) return;
    int s = src[e], d = dst[e];
    int p = atomicAdd(&cur[d], 1);
    int slot = rowp[d] + p;
    es[slot] = s;
    en[slot] = dinv[s] * dinv[d];
}

// ---------------- weight / bias pre-pack ----------------
// s 0..13 (edge pipeline, 32x32x16 A-operand layout):
//   frag pair q = mo*4+kts (mo: out-feat 32-tile, kts: K=16 slice)
//   uint4 at: s*1024 + (q*2+h)*64 + lane   (h=0 hi, h=1 lo)
//   bf16[i] = W_s[fi][fo], fi = 16*kts + 8*(lane>>5) + i, fo = 32*mo + (lane&31)
// s 14..17 (gcn, 16x16x32 B-operand layout, unchanged): [s][kt][nt][lane][8u32]

__global__ __launch_bounds__(256) void k_wprep(const float* __restrict__ ew0, const float* __restrict__ ew,
                                               const float* __restrict__ ow0, const float* __restrict__ ow,
                                               const float* __restrict__ gw, unsigned* __restrict__ wpk) {
    int t = blockIdx.x * 256 + threadIdx.x;
    if (t >= 18 * 512) return;
    int lane = t & 63;
    int s = t >> 9;
    unsigned hu[8], lu[8];
    if (s < 14) {
        int q = (t >> 6) & 7;
        int mo = q >> 2, kts = q & 3;
        int fo = 32 * mo + (lane & 31);
#pragma unroll
        for (int i = 0; i < 8; ++i) {
            int fi = 16 * kts + 8 * (lane >> 5) + i;
            float w = 0.f;
            if (s == 0)       { if (fi < 16) w = ew0[fi * 64 + fo]; }
            else if (s <= 7)  w = ew[((s - 1) * 64 + fi) * 64 + fo];
            else if (s == 8)  w = ow0[(128 + fi) * 64 + fo];
            else if (s == 9)  w = ow0[fi * 64 + fo];
            else if (s == 10) w = ow0[(64 + fi) * 64 + fo];
            else              w = ow[((s - 11) * 64 + fi) * 64 + fo];
            unsigned u = __float_as_uint(w);
            unsigned h = u & 0xFFFF0000u;
            float d = w - __uint_as_float(h);
            hu[i] = h >> 16;
            lu[i] = __float_as_uint(d) >> 16;
        }
        uint4* o = (uint4*)wpk + (size_t)s * 1024 + (q * 2) * 64 + lane;
        o[0]  = make_uint4(hu[0] | (hu[1] << 16), hu[2] | (hu[3] << 16), hu[4] | (hu[5] << 16), hu[6] | (hu[7] << 16));
        o[64] = make_uint4(lu[0] | (lu[1] << 16), lu[2] | (lu[3] << 16), lu[4] | (lu[5] << 16), lu[6] | (lu[7] << 16));
    } else {
        int nt = (t >> 6) & 3;
        int kt = (t >> 8) & 1;
        int n = nt * 16 + (lane & 15);
#pragma unroll
        for (int i = 0; i < 8; ++i) {
            int k = kt * 32 + ((lane >> 4) * 8) + i;
            float w = gw[((s - 14) * 64 + k) * 64 + n];
            unsigned u = __float_as_uint(w);
            unsigned h = u & 0xFFFF0000u;
            float d = w - __uint_as_float(h);
            hu[i] = h >> 16;
            lu[i] = __float_as_uint(d) >> 16;
        }
        uint4* o = (uint4*)(wpk + (size_t)t * 8);
        o[0] = make_uint4(hu[0] | (hu[1] << 16), hu[2] | (hu[3] << 16), hu[4] | (hu[5] << 16), hu[6] | (hu[7] << 16));
        o[1] = make_uint4(lu[0] | (lu[1] << 16), lu[2] | (lu[3] << 16), lu[4] | (lu[5] << 16), lu[6] | (lu[7] << 16));
    }
}

// bias3: idx = s*64 + mo*32 + q*8 + l5*4 + j  <->  feat f = 32mo + 8q + 4l5 + j
// slot 14 = fin_w (same pattern), bias3[15*64] = fin_b
__global__ __launch_bounds__(256) void k_bprep(const float* __restrict__ eb0, const float* __restrict__ eb,
                                               const float* __restrict__ ob0, const float* __restrict__ ob,
                                               const float* __restrict__ finw, const float* __restrict__ finb,
                                               float* __restrict__ bias3) {
    int t = blockIdx.x * 256 + threadIdx.x;
    if (t > 15 * 64) return;
    if (t == 15 * 64) { bias3[t] = finb[0]; return; }
    int s = t >> 6, idx = t & 63;
    int j = idx & 3, l5 = (idx >> 2) & 1, q = (idx >> 3) & 3, mo = idx >> 5;
    int f = 32 * mo + 8 * q + 4 * l5 + j;
    float b = 0.f;
    if (s == 0) b = eb0[f];
    else if (s <= 7) b = eb[(s - 1) * 64 + f];
    else if (s == 8) b = ob0[f];
    else if (s >= 11 && s <= 13) b = ob[(s - 11) * 64 + f];
    else if (s == 14) b = finw[f];
    bias3[t] = b;
}

// ---------------- shared split helpers ----------------

__device__ __forceinline__ void split_pack8(const float* xv, uint4& hfrag, uint4& lfrag) {
    unsigned hu[8], lu[8];
#pragma unroll
    for (int i = 0; i < 8; ++i) {
        unsigned u = __float_as_uint(xv[i]);
        unsigned h = u & 0xFFFF0000u;
        float d = xv[i] - __uint_as_float(h);
        hu[i] = h >> 16;
        lu[i] = __float_as_uint(d) >> 16;
    }
    hfrag = make_uint4(hu[0] | (hu[1] << 16), hu[2] | (hu[3] << 16), hu[4] | (hu[5] << 16), hu[6] | (hu[7] << 16));
    lfrag = make_uint4(lu[0] | (lu[1] << 16), lu[2] | (lu[3] << 16), lu[4] | (lu[5] << 16), lu[6] | (lu[7] << 16));
}

__device__ __forceinline__ void load_a_global_kt(const float* rowp, int kt, int g, uint4& aH, uint4& aL) {
    const float4* r4 = (const float4*)(rowp + kt * 32 + g * 8);
    float4 f0 = r4[0], f1 = r4[1];
    float xv[8] = {f0.x, f0.y, f0.z, f0.w, f1.x, f1.y, f1.z, f1.w};
    split_pack8(xv, aH, aL);
}

// 16x16x32 B-operand mfma (gcn node GEMM only)
__device__ __forceinline__ void mfma_stage(f32x4 acc[2][4], const uint4* wqs,
                                           const uint4 aH[2][2], const uint4 aL[2][2], int lane) {
#pragma unroll
    for (int kt = 0; kt < 2; ++kt) {
#pragma unroll
        for (int nt = 0; nt < 4; ++nt) {
            const uint4* wq = wqs + ((size_t)((kt * 4 + nt) * 64 + lane)) * 2;
            short8v bh = as_frag(wq[0]);
            short8v bl = as_frag(wq[1]);
#pragma unroll
            for (int mt = 0; mt < 2; ++mt) {
                short8v ah = as_frag(aH[mt][kt]);
                short8v al = as_frag(aL[mt][kt]);
                acc[mt][nt] = __builtin_amdgcn_mfma_f32_16x16x32_bf16(ah, bh, acc[mt][nt], 0, 0, 0);
                acc[mt][nt] = __builtin_amdgcn_mfma_f32_16x16x32_bf16(al, bh, acc[mt][nt], 0, 0, 0);
                acc[mt][nt] = __builtin_amdgcn_mfma_f32_16x16x32_bf16(ah, bl, acc[mt][nt], 0, 0, 0);
            }
        }
    }
}

// ---------------- GCN node GEMM (unchanged from R4/R5) ----------------

__global__ __launch_bounds__(256, 3) void k_xlm(const float* __restrict__ xin,
                                                const unsigned* __restrict__ wpk, int stage,
                                                float* __restrict__ xl) {
    const int tid = threadIdx.x;
    const int wv = tid >> 6, lane = tid & 63;
    const int g = lane >> 4, l15 = lane & 15;
    const int rb = blockIdx.x * 128 + wv * 32;
    const uint4* wq = (const uint4*)wpk + (size_t)stage * 1024;

    f32x4 acc[2][4];
    uint4 aH[2][2], aL[2][2];
#pragma unroll
    for (int mt = 0; mt < 2; ++mt) {
        int row = rb + mt * 16 + l15;
        if (row < N_NODES) {
            const float* rowp = xin + (size_t)row * 64;
#pragma unroll
            for (int kt = 0; kt < 2; ++kt) load_a_global_kt(rowp, kt, g, aH[mt][kt], aL[mt][kt]);
        } else {
#pragma unroll
            for (int kt = 0; kt < 2; ++kt) { aH[mt][kt] = zero4(); aL[mt][kt] = zero4(); }
        }
#pragma unroll
        for (int nt = 0; nt < 4; ++nt) acc[mt][nt] = (f32x4){0.f, 0.f, 0.f, 0.f};
    }
    mfma_stage(acc, wq, aH, aL, lane);
#pragma unroll
    for (int mt = 0; mt < 2; ++mt)
#pragma unroll
        for (int nt = 0; nt < 4; ++nt)
#pragma unroll
            for (int r = 0; r < 4; ++r) {
                int row = rb + mt * 16 + g * 4 + r;
                if (row < N_NODES) xl[(size_t)row * 64 + nt * 16 + l15] = acc[mt][nt][r];
            }
}

// ---------------- segmented aggregation (+ optional split output) ----------------

__global__ __launch_bounds__(256) void k_agg(const float* __restrict__ xl,
                                             const int* __restrict__ es, const float* __restrict__ en,
                                             const int* __restrict__ rowp, const float* __restrict__ dinv,
                                             const float* __restrict__ b, float* __restrict__ xout,
                                             unsigned short* __restrict__ oh, unsigned short* __restrict__ ol,
                                             int writeSplit) {
    int n = blockIdx.x * 4 + (threadIdx.x >> 6);
    int j = threadIdx.x & 63;
    if (n >= N_NODES) return;
    int i = rowp[n], e1 = rowp[n + 1];
    float a0 = 0.f, a1 = 0.f;
    for (; i + 1 < e1; i += 2) {
        int s0 = es[i], s1 = es[i + 1];
        float w0 = en[i], w1 = en[i + 1];
        a0 = fmaf(w0, xl[(size_t)s0 * 64 + j], a0);
        a1 = fmaf(w1, xl[(size_t)s1 * 64 + j], a1);
    }
    if (i < e1) a0 = fmaf(en[i], xl[(size_t)es[i] * 64 + j], a0);
    float di = dinv[n];
    float val = a0 + a1 + di * di * xl[(size_t)n * 64 + j] + b[j];
    float v = fmaxf(val, 0.f);
    size_t idx = (size_t)n * 64 + j;
    xout[idx] = v;
    if (writeSplit) {
        unsigned u = __float_as_uint(v);
        oh[idx] = (unsigned short)(u >> 16);
        float d = v - __uint_as_float(u & 0xFFFF0000u);
        ol[idx] = (unsigned short)(__float_as_uint(d) >> 16);
    }
}

// ---------------- fused edge mega kernel v4: 32x32x16 + permlane32_swap ----------------
// wave = 32 edges (n = lane&31); acc = f32x16[2] (64 out feats).
// Inter-stage transpose: relu+split+cvt_pk, then 1 permlane32_swap per word-pair.
// Weights double-buffered in LDS (16KB/stage), staged T14-style, 1 barrier/stage.

__device__ __forceinline__ void bias_init32(f32x16 acc[2], const float* bp) {
#pragma unroll
    for (int mo = 0; mo < 2; ++mo)
#pragma unroll
        for (int q = 0; q < 4; ++q) {
            float4 b = *(const float4*)(bp + (mo * 4 + q) * 8);
            acc[mo][4 * q + 0] = b.x;
            acc[mo][4 * q + 1] = b.y;
            acc[mo][4 * q + 2] = b.z;
            acc[mo][4 * q + 3] = b.w;
        }
}

// relu + split + native transpose via permlane32_swap.
// For slice kts: uses acc[kts>>1] elements 8*(kts&1)..+7.
// l5=0 lanes keep own quadA words, receive partner quadA; l5=1 receive partner quadB, keep own quadB.
__device__ __forceinline__ void exchange32(const f32x16 acc[2], unsigned BH[4][4], unsigned BL[4][4]) {
#pragma unroll
    for (int kts = 0; kts < 4; ++kts) {
        const int mo = kts >> 1;
        const int base = 8 * (kts & 1);
        float r0 = fmaxf(acc[mo][base + 0], 0.f), r1 = fmaxf(acc[mo][base + 1], 0.f);
        float r2 = fmaxf(acc[mo][base + 2], 0.f), r3 = fmaxf(acc[mo][base + 3], 0.f);
        float r4 = fmaxf(acc[mo][base + 4], 0.f), r5 = fmaxf(acc[mo][base + 5], 0.f);
        float r6 = fmaxf(acc[mo][base + 6], 0.f), r7 = fmaxf(acc[mo][base + 7], 0.f);
        unsigned pA0, pA1, pB0, pB1;
        asm("v_cvt_pk_bf16_f32 %0, %1, %2" : "=v"(pA0) : "v"(r0), "v"(r1));
        asm("v_cvt_pk_bf16_f32 %0, %1, %2" : "=v"(pA1) : "v"(r2), "v"(r3));
        asm("v_cvt_pk_bf16_f32 %0, %1, %2" : "=v"(pB0) : "v"(r4), "v"(r5));
        asm("v_cvt_pk_bf16_f32 %0, %1, %2" : "=v"(pB1) : "v"(r6), "v"(r7));
        float d0 = r0 - __uint_as_float(pA0 << 16);
        float d1 = r1 - __uint_as_float(pA0 & 0xFFFF0000u);
        float d2 = r2 - __uint_as_float(pA1 << 16);
        float d3 = r3 - __uint_as_float(pA1 & 0xFFFF0000u);
        float d4 = r4 - __uint_as_float(pB0 << 16);
        float d5 = r5 - __uint_as_float(pB0 & 0xFFFF0000u);
        float d6 = r6 - __uint_as_float(pB1 << 16);
        float d7 = r7 - __uint_as_float(pB1 & 0xFFFF0000u);
        unsigned qA0, qA1, qB0, qB1;
        asm("v_cvt_pk_bf16_f32 %0, %1, %2" : "=v"(qA0) : "v"(d0), "v"(d1));
        asm("v_cvt_pk_bf16_f32 %0, %1, %2" : "=v"(qA1) : "v"(d2), "v"(d3));
        asm("v_cvt_pk_bf16_f32 %0, %1, %2" : "=v"(qB0) : "v"(d4), "v"(d5));
        asm("v_cvt_pk_bf16_f32 %0, %1, %2" : "=v"(qB1) : "v"(d6), "v"(d7));
        uint2v sw0 = __builtin_amdgcn_permlane32_swap(pA0, pB0, false, false);
        uint2v sw1 = __builtin_amdgcn_permlane32_swap(pA1, pB1, false, false);
        BH[kts][0] = sw0[0]; BH[kts][1] = sw1[0]; BH[kts][2] = sw0[1]; BH[kts][3] = sw1[1];
        uint2v tw0 = __builtin_amdgcn_permlane32_swap(qA0, qB0, false, false);
        uint2v tw1 = __builtin_amdgcn_permlane32_swap(qA1, qB1, false, false);
        BL[kts][0] = tw0[0]; BL[kts][1] = tw1[0]; BL[kts][2] = tw0[1]; BL[kts][3] = tw1[1];
    }
}

__device__ __forceinline__ void loadB32(const unsigned short* xhi, const unsigned short* xlo,
                                        int node, int l5, unsigned BH[4][4], unsigned BL[4][4]) {
    const uint4* hp = (const uint4*)xhi + (size_t)node * 8;
    const uint4* lp = (const uint4*)xlo + (size_t)node * 8;
#pragma unroll
    for (int kts = 0; kts < 4; ++kts) {
        uint4 h = hp[2 * kts + l5];
        BH[kts][0] = h.x; BH[kts][1] = h.y; BH[kts][2] = h.z; BH[kts][3] = h.w;
        uint4 l = lp[2 * kts + l5];
        BL[kts][0] = l.x; BL[kts][1] = l.y; BL[kts][2] = l.z; BL[kts][3] = l.w;
    }
}

template <int KTS>
__device__ __forceinline__ void mfma32(f32x16 acc[2], const uint4* wl,
                                       const unsigned BH[4][4], const unsigned BL[4][4], int lane) {
#pragma unroll
    for (int kt = 0; kt < KTS; ++kt) {
        short8v Bh = as_frag(make_uint4(BH[kt][0], BH[kt][1], BH[kt][2], BH[kt][3]));
        short8v Bl = as_frag(make_uint4(BL[kt][0], BL[kt][1], BL[kt][2], BL[kt][3]));
#pragma unroll
        for (int mo = 0; mo < 2; ++mo) {
            short8v Ah = as_frag(wl[((mo * 4 + kt) * 2 + 0) * 64 + lane]);
            short8v Al = as_frag(wl[((mo * 4 + kt) * 2 + 1) * 64 + lane]);
            acc[mo] = __builtin_amdgcn_mfma_f32_32x32x16_bf16(Ah, Bh, acc[mo], 0, 0, 0);
            acc[mo] = __builtin_amdgcn_mfma_f32_32x32x16_bf16(Al, Bh, acc[mo], 0, 0, 0);
            acc[mo] = __builtin_amdgcn_mfma_f32_32x32x16_bf16(Ah, Bl, acc[mo], 0, 0, 0);
        }
    }
}

__global__ __launch_bounds__(256, 3) void k_mega(
    const float* __restrict__ ea, const int* __restrict__ src, const int* __restrict__ dst,
    const unsigned short* __restrict__ xhi, const unsigned short* __restrict__ xlo,
    const unsigned* __restrict__ wpk, const float* __restrict__ bias3,
    float* __restrict__ out) {
    __shared__ uint4 wlds[2][1024];   // 2 x 16 KB weight double-buffer
    const int tid = threadIdx.x;
    const int wv = tid >> 6, lane = tid & 63;
    const int l5 = lane >> 5, n = lane & 31;
    const int e = blockIdx.x * 128 + wv * 32 + n;
    const uint4* wpk4 = (const uint4*)wpk;

    // prologue: stage-0 weights into buffer 0
#pragma unroll
    for (int j = 0; j < 4; ++j) wlds[0][tid + 256 * j] = wpk4[tid + 256 * j];

    // edge node indices (hoisted)
    const int nsrc = src[e];
    const int ndst = dst[e];

    f32x16 acc[2];
    unsigned BH[4][4], BL[4][4];

    // s0 B-frags from edge_attr (K=16, slice 0 only)
    {
        const float4* ar = (const float4*)(ea + (size_t)e * 16 + 8 * l5);
        float4 f0 = ar[0], f1 = ar[1];
        float xv[8] = {f0.x, f0.y, f0.z, f0.w, f1.x, f1.y, f1.z, f1.w};
        uint4 hf, lf;
        split_pack8(xv, hf, lf);
        BH[0][0] = hf.x; BH[0][1] = hf.y; BH[0][2] = hf.z; BH[0][3] = hf.w;
        BL[0][0] = lf.x; BL[0][1] = lf.y; BL[0][2] = lf.z; BL[0][3] = lf.w;
    }
    __syncthreads();

    for (int s = 0; s < 14; ++s) {
        uint4 st0, st1, st2, st3;
        if (s < 13) {   // issue next-stage weight loads early (T14)
            const uint4* np = wpk4 + (size_t)(s + 1) * 1024;
            st0 = np[tid]; st1 = np[tid + 256]; st2 = np[tid + 512]; st3 = np[tid + 768];
        }
        const uint4* wl = wlds[s & 1];
        if (s == 0) {
            bias_init32(acc, bias3 + l5 * 4);
            mfma32<1>(acc, wl, BH, BL, lane);
        } else if (s == 9 || s == 10) {
            loadB32(xhi, xlo, (s == 9) ? nsrc : ndst, l5, BH, BL);
            mfma32<4>(acc, wl, BH, BL, lane);     // accumulate into out-MLP acc
        } else {
            exchange32(acc, BH, BL);
            bias_init32(acc, bias3 + s * 64 + l5 * 4);
            mfma32<4>(acc, wl, BH, BL, lane);
        }
        if (s < 13) {   // write-late into the other buffer
            uint4* nb = wlds[(s + 1) & 1];
            nb[tid] = st0; nb[tid + 256] = st1; nb[tid + 512] = st2; nb[tid + 768] = st3;
        }
        __syncthreads();
    }

    // final dot: out = relu(P14)^T . fin_w + fin_b
    float v = 0.f;
#pragma unroll
    for (int mo = 0; mo < 2; ++mo)
#pragma unroll
        for (int q = 0; q < 4; ++q) {
            float4 w4 = *(const float4*)(bias3 + 14 * 64 + (mo * 4 + q) * 8 + l5 * 4);
            v = fmaf(fmaxf(acc[mo][4 * q + 0], 0.f), w4.x, v);
            v = fmaf(fmaxf(acc[mo][4 * q + 1], 0.f), w4.y, v);
            v = fmaf(fmaxf(acc[mo][4 * q + 2], 0.f), w4.z, v);
            v = fmaf(fmaxf(acc[mo][4 * q + 3], 0.f), w4.w, v);
        }
    v += __shfl_xor(v, 32, 64);
    if (lane < 32) out[e] = v + bias3[15 * 64];
}

// ---------------- launch ----------------

extern "C" void kernel_launch(void* const* d_in, const int* in_sizes, int n_in,
                              void* d_out, int out_size, void* d_ws, size_t ws_size,
                              hipStream_t stream) {
    (void)in_sizes; (void)n_in; (void)out_size; (void)ws_size;

    const float* x         = (const float*)d_in[0];
    const int*   src       = (const int*)d_in[1];
    const int*   dst       = (const int*)d_in[2];
    const float* edge_attr = (const float*)d_in[3];
    const float* gcn_w     = (const float*)d_in[4];
    const float* gcn_b     = (const float*)d_in[5];
    const float* edge_w0   = (const float*)d_in[6];
    const float* edge_b0   = (const float*)d_in[7];
    const float* edge_w    = (const float*)d_in[8];
    const float* edge_b    = (const float*)d_in[9];
    const float* out_w0    = (const float*)d_in[10];
    const float* out_b0    = (const float*)d_in[11];
    const float* out_w     = (const float*)d_in[12];
    const float* out_b     = (const float*)d_in[13];
    const float* fin_w     = (const float*)d_in[14];
    const float* fin_b     = (const float*)d_in[15];
    float* out = (float*)d_out;

    float* ws    = (float*)d_ws;
    float* dinv  = ws;                                  // NPAD
    float* xbufA = dinv + NPAD;                         // N*64
    float* xl    = xbufA + N_NODES * 64;                // N*64
    unsigned short* xhi = (unsigned short*)(xl + N_NODES * 64);   // N*64 u16
    unsigned short* xlo = xhi + N_NODES * 64;                     // N*64 u16
    float* scr   = (float*)(xlo + N_NODES * 64);
    unsigned* wpk   = (unsigned*)scr;                   // 18*4096 = 73728 u32
    float* bias3    = scr + 73728;                      // 961 (pad 1088)
    int* degi       = (int*)(scr + 74816);              // NPAD
    int* cur        = degi + NPAD;                      // NPAD (adjacent for one memset)
    int* part       = cur + NPAD;                       // NPAD
    int* bsum       = part + NPAD;                      // 256
    int* rowp       = bsum + 256;                       // NPAD
    int* es         = rowp + NPAD;                      // E
    float* en       = (float*)(es + N_EDGES);           // E

    const int EB = N_EDGES / 256;                       // 3125
    const int NB = NPAD / 256;                          // 196

    hipMemsetAsync(degi, 0, 2 * NPAD * sizeof(int), stream);
    k_deg_i<<<EB, 256, 0, stream>>>(dst, degi);
    k_scan1<<<NB, 256, 0, stream>>>(degi, part, bsum, dinv);
    k_scan2<<<1, 256, 0, stream>>>(bsum);
    k_scan3<<<NB, 256, 0, stream>>>(part, bsum, rowp);
    k_place<<<EB, 256, 0, stream>>>(src, dst, dinv, rowp, cur, es, en);

    k_wprep<<<36, 256, 0, stream>>>(edge_w0, edge_w, out_w0, out_w, gcn_w, wpk);
    k_bprep<<<4, 256, 0, stream>>>(edge_b0, edge_b, out_b0, out_b, fin_w, fin_b, bias3);

    const float* xin = x;
    for (int layer = 0; layer < 4; ++layer) {
        k_xlm<<<(NPAD / 128), 256, 0, stream>>>(xin, wpk, 14 + layer, xl);
        k_agg<<<(N_NODES + 3) / 4, 256, 0, stream>>>(xl, es, en, rowp, dinv,
                                                     gcn_b + layer * 64, xbufA,
                                                     xhi, xlo, (layer == 3) ? 1 : 0);
        xin = xbufA;
    }

    k_mega<<<N_EDGES / 128, 256, 0, stream>>>(edge_attr, src, dst, xhi, xlo,
                                              wpk, bias3, out);
}

// Round 7
// 585.377 us; speedup vs baseline: 1.4663x; 1.0366x over previous
//
#include <hip/hip_runtime.h>

#define N_NODES 50000
#define N_EDGES 800000
#define NPAD 50176   // 196*256

typedef __attribute__((ext_vector_type(8))) short short8v;   // 8 bf16 (4 VGPR)
typedef __attribute__((ext_vector_type(4))) float f32x4;
typedef __attribute__((ext_vector_type(16))) float f32x16;
typedef __attribute__((ext_vector_type(2))) unsigned uint2v;

union U4S8 { uint4 u; short8v s; };
__device__ __forceinline__ short8v as_frag(uint4 u) { U4S8 t; t.u = u; return t.s; }
__device__ __forceinline__ uint4 zero4() { return make_uint4(0u, 0u, 0u, 0u); }

// ---------------- degree / CSR build ----------------

__global__ __launch_bounds__(256) void k_deg_i(const int* __restrict__ dst, int* __restrict__ degi) {
    int e = blockIdx.x * 256 + threadIdx.x;
    if (e < N_EDGES) atomicAdd(&degi[dst[e]], 1);
}

__global__ __launch_bounds__(256) void k_scan1(const int* __restrict__ degi, int* __restrict__ part,
                                               int* __restrict__ bsum, float* __restrict__ dinv) {
    __shared__ int tmp[256];
    int t = threadIdx.x, gid = blockIdx.x * 256 + t;
    int v = degi[gid];
    if (gid < N_NODES) dinv[gid] = rsqrtf((float)v + 1.0f);
    tmp[t] = v;
    __syncthreads();
    for (int off = 1; off < 256; off <<= 1) {
        int add = (t >= off) ? tmp[t - off] : 0;
        __syncthreads();
        tmp[t] += add;
        __syncthreads();
    }
    part[gid] = tmp[t] - v;
    if (t == 255) bsum[blockIdx.x] = tmp[t];
}

__global__ __launch_bounds__(256) void k_scan2(int* __restrict__ bsum) {
    __shared__ int tmp[256];
    int t = threadIdx.x;
    int v = (t < 196) ? bsum[t] : 0;
    tmp[t] = v;
    __syncthreads();
    for (int off = 1; off < 256; off <<= 1) {
        int add = (t >= off) ? tmp[t - off] : 0;
        __syncthreads();
        tmp[t] += add;
        __syncthreads();
    }
    if (t < 196) bsum[t] = tmp[t] - v;
}

__global__ __launch_bounds__(256) void k_scan3(const int* __restrict__ part, const int* __restrict__ bsum,
                                               int* __restrict__ rowp) {
    int gid = blockIdx.x * 256 + threadIdx.x;
    rowp[gid] = part[gid] + bsum[blockIdx.x];
}

__global__ __launch_bounds__(256) void k_place(const int* __restrict__ src, const int* __restrict__ dst,
                                               const float* __restrict__ dinv, const int* __restrict__ rowp,
                                               int* __restrict__ cur, int* __restrict__ es, float* __restrict__ en) {
    int e = blockIdx.x * 256 + threadIdx.x;
    if (e >= N_EDGES) return;
    int s = src[e], d = dst[e];
    int p = atomicAdd(&cur[d], 1);
    int slot = rowp[d] + p;
    es[slot] = s;
    en[slot] = dinv[s] * dinv[d];
}

// ---------------- weight / bias pre-pack ----------------
// s 0..13 (edge pipeline, 32x32x16 A-operand layout):
//   frag pair q = mo*4+kts (mo: out-feat 32-tile, kts: K=16 slice)
//   uint4 at: s*1024 + (q*2+h)*64 + lane   (h=0 hi, h=1 lo)
//   bf16[i] = W_s[fi][fo], fi = 16*kts + 8*(lane>>5) + i, fo = 32*mo + (lane&31)
// s 14..17 (gcn, 16x16x32 B-operand layout): [s][kt][nt][lane][8u32]

__global__ __launch_bounds__(256) void k_wprep(const float* __restrict__ ew0, const float* __restrict__ ew,
                                               const float* __restrict__ ow0, const float* __restrict__ ow,
                                               const float* __restrict__ gw, unsigned* __restrict__ wpk) {
    int t = blockIdx.x * 256 + threadIdx.x;
    if (t >= 18 * 512) return;
    int lane = t & 63;
    int s = t >> 9;
    unsigned hu[8], lu[8];
    if (s < 14) {
        int q = (t >> 6) & 7;
        int mo = q >> 2, kts = q & 3;
        int fo = 32 * mo + (lane & 31);
#pragma unroll
        for (int i = 0; i < 8; ++i) {
            int fi = 16 * kts + 8 * (lane >> 5) + i;
            float w = 0.f;
            if (s == 0)       { if (fi < 16) w = ew0[fi * 64 + fo]; }
            else if (s <= 7)  w = ew[((s - 1) * 64 + fi) * 64 + fo];
            else if (s == 8)  w = ow0[(128 + fi) * 64 + fo];
            else if (s == 9)  w = ow0[fi * 64 + fo];
            else if (s == 10) w = ow0[(64 + fi) * 64 + fo];
            else              w = ow[((s - 11) * 64 + fi) * 64 + fo];
            unsigned u = __float_as_uint(w);
            unsigned h = u & 0xFFFF0000u;
            float d = w - __uint_as_float(h);
            hu[i] = h >> 16;
            lu[i] = __float_as_uint(d) >> 16;
        }
        uint4* o = (uint4*)wpk + (size_t)s * 1024 + (q * 2) * 64 + lane;
        o[0]  = make_uint4(hu[0] | (hu[1] << 16), hu[2] | (hu[3] << 16), hu[4] | (hu[5] << 16), hu[6] | (hu[7] << 16));
        o[64] = make_uint4(lu[0] | (lu[1] << 16), lu[2] | (lu[3] << 16), lu[4] | (lu[5] << 16), lu[6] | (lu[7] << 16));
    } else {
        int nt = (t >> 6) & 3;
        int kt = (t >> 8) & 1;
        int n = nt * 16 + (lane & 15);
#pragma unroll
        for (int i = 0; i < 8; ++i) {
            int k = kt * 32 + ((lane >> 4) * 8) + i;
            float w = gw[((s - 14) * 64 + k) * 64 + n];
            unsigned u = __float_as_uint(w);
            unsigned h = u & 0xFFFF0000u;
            float d = w - __uint_as_float(h);
            hu[i] = h >> 16;
            lu[i] = __float_as_uint(d) >> 16;
        }
        uint4* o = (uint4*)(wpk + (size_t)t * 8);
        o[0] = make_uint4(hu[0] | (hu[1] << 16), hu[2] | (hu[3] << 16), hu[4] | (hu[5] << 16), hu[6] | (hu[7] << 16));
        o[1] = make_uint4(lu[0] | (lu[1] << 16), lu[2] | (lu[3] << 16), lu[4] | (lu[5] << 16), lu[6] | (lu[7] << 16));
    }
}

// bias3: idx = s*64 + mo*32 + q*8 + l5*4 + j  <->  feat f = 32mo + 8q + 4l5 + j
// slot 14 = fin_w (same pattern), bias3[15*64] = fin_b
__global__ __launch_bounds__(256) void k_bprep(const float* __restrict__ eb0, const float* __restrict__ eb,
                                               const float* __restrict__ ob0, const float* __restrict__ ob,
                                               const float* __restrict__ finw, const float* __restrict__ finb,
                                               float* __restrict__ bias3) {
    int t = blockIdx.x * 256 + threadIdx.x;
    if (t >= 1024) return;
    if (t == 15 * 64) { bias3[t] = finb[0]; return; }
    if (t > 15 * 64)  { bias3[t] = 0.f; return; }
    int s = t >> 6, idx = t & 63;
    int j = idx & 3, l5 = (idx >> 2) & 1, q = (idx >> 3) & 3, mo = idx >> 5;
    int f = 32 * mo + 8 * q + 4 * l5 + j;
    float b = 0.f;
    if (s == 0) b = eb0[f];
    else if (s <= 7) b = eb[(s - 1) * 64 + f];
    else if (s == 8) b = ob0[f];
    else if (s >= 11 && s <= 13) b = ob[(s - 11) * 64 + f];
    else if (s == 14) b = finw[f];
    bias3[t] = b;
}

// ---------------- shared split helpers ----------------

__device__ __forceinline__ void split_pack8(const float* xv, uint4& hfrag, uint4& lfrag) {
    unsigned hu[8], lu[8];
#pragma unroll
    for (int i = 0; i < 8; ++i) {
        unsigned u = __float_as_uint(xv[i]);
        unsigned h = u & 0xFFFF0000u;
        float d = xv[i] - __uint_as_float(h);
        hu[i] = h >> 16;
        lu[i] = __float_as_uint(d) >> 16;
    }
    hfrag = make_uint4(hu[0] | (hu[1] << 16), hu[2] | (hu[3] << 16), hu[4] | (hu[5] << 16), hu[6] | (hu[7] << 16));
    lfrag = make_uint4(lu[0] | (lu[1] << 16), lu[2] | (lu[3] << 16), lu[4] | (lu[5] << 16), lu[6] | (lu[7] << 16));
}

__device__ __forceinline__ void load_a_global_kt(const float* rowp, int kt, int g, uint4& aH, uint4& aL) {
    const float4* r4 = (const float4*)(rowp + kt * 32 + g * 8);
    float4 f0 = r4[0], f1 = r4[1];
    float xv[8] = {f0.x, f0.y, f0.z, f0.w, f1.x, f1.y, f1.z, f1.w};
    split_pack8(xv, aH, aL);
}

// 16x16x32 B-operand mfma (gcn node GEMM only)
__device__ __forceinline__ void mfma_stage(f32x4 acc[2][4], const uint4* wqs,
                                           const uint4 aH[2][2], const uint4 aL[2][2], int lane) {
#pragma unroll
    for (int kt = 0; kt < 2; ++kt) {
#pragma unroll
        for (int nt = 0; nt < 4; ++nt) {
            const uint4* wq = wqs + ((size_t)((kt * 4 + nt) * 64 + lane)) * 2;
            short8v bh = as_frag(wq[0]);
            short8v bl = as_frag(wq[1]);
#pragma unroll
            for (int mt = 0; mt < 2; ++mt) {
                short8v ah = as_frag(aH[mt][kt]);
                short8v al = as_frag(aL[mt][kt]);
                acc[mt][nt] = __builtin_amdgcn_mfma_f32_16x16x32_bf16(ah, bh, acc[mt][nt], 0, 0, 0);
                acc[mt][nt] = __builtin_amdgcn_mfma_f32_16x16x32_bf16(al, bh, acc[mt][nt], 0, 0, 0);
                acc[mt][nt] = __builtin_amdgcn_mfma_f32_16x16x32_bf16(ah, bl, acc[mt][nt], 0, 0, 0);
            }
        }
    }
}

// ---------------- GCN node GEMM ----------------

__global__ __launch_bounds__(256, 3) void k_xlm(const float* __restrict__ xin,
                                                const unsigned* __restrict__ wpk, int stage,
                                                float* __restrict__ xl) {
    const int tid = threadIdx.x;
    const int wv = tid >> 6, lane = tid & 63;
    const int g = lane >> 4, l15 = lane & 15;
    const int rb = blockIdx.x * 128 + wv * 32;
    const uint4* wq = (const uint4*)wpk + (size_t)stage * 1024;

    f32x4 acc[2][4];
    uint4 aH[2][2], aL[2][2];
#pragma unroll
    for (int mt = 0; mt < 2; ++mt) {
        int row = rb + mt * 16 + l15;
        if (row < N_NODES) {
            const float* rowp = xin + (size_t)row * 64;
#pragma unroll
            for (int kt = 0; kt < 2; ++kt) load_a_global_kt(rowp, kt, g, aH[mt][kt], aL[mt][kt]);
        } else {
#pragma unroll
            for (int kt = 0; kt < 2; ++kt) { aH[mt][kt] = zero4(); aL[mt][kt] = zero4(); }
        }
#pragma unroll
        for (int nt = 0; nt < 4; ++nt) acc[mt][nt] = (f32x4){0.f, 0.f, 0.f, 0.f};
    }
    mfma_stage(acc, wq, aH, aL, lane);
#pragma unroll
    for (int mt = 0; mt < 2; ++mt)
#pragma unroll
        for (int nt = 0; nt < 4; ++nt)
#pragma unroll
            for (int r = 0; r < 4; ++r) {
                int row = rb + mt * 16 + g * 4 + r;
                if (row < N_NODES) xl[(size_t)row * 64 + nt * 16 + l15] = acc[mt][nt][r];
            }
}

// ---------------- segmented aggregation (+ optional split output) ----------------

__global__ __launch_bounds__(256) void k_agg(const float* __restrict__ xl,
                                             const int* __restrict__ es, const float* __restrict__ en,
                                             const int* __restrict__ rowp, const float* __restrict__ dinv,
                                             const float* __restrict__ b, float* __restrict__ xout,
                                             unsigned short* __restrict__ oh, unsigned short* __restrict__ ol,
                                             int writeSplit) {
    int n = blockIdx.x * 4 + (threadIdx.x >> 6);
    int j = threadIdx.x & 63;
    if (n >= N_NODES) return;
    int i = rowp[n], e1 = rowp[n + 1];
    float a0 = 0.f, a1 = 0.f;
    for (; i + 1 < e1; i += 2) {
        int s0 = es[i], s1 = es[i + 1];
        float w0 = en[i], w1 = en[i + 1];
        a0 = fmaf(w0, xl[(size_t)s0 * 64 + j], a0);
        a1 = fmaf(w1, xl[(size_t)s1 * 64 + j], a1);
    }
    if (i < e1) a0 = fmaf(en[i], xl[(size_t)es[i] * 64 + j], a0);
    float di = dinv[n];
    float val = a0 + a1 + di * di * xl[(size_t)n * 64 + j] + b[j];
    float v = fmaxf(val, 0.f);
    size_t idx = (size_t)n * 64 + j;
    xout[idx] = v;
    if (writeSplit) {
        unsigned u = __float_as_uint(v);
        oh[idx] = (unsigned short)(u >> 16);
        float d = v - __uint_as_float(u & 0xFFFF0000u);
        ol[idx] = (unsigned short)(__float_as_uint(d) >> 16);
    }
}

// ---------------- fused edge mega kernel v4: 32x32x16 + permlane32_swap ----------------
// wave = 32 edges (n = lane&31); acc = f32x16[2] (64 out feats).
// Inter-stage transpose: relu+split+cvt_pk, then 1 permlane32_swap per word-pair.
// Weights double-buffered in LDS (16KB/stage), staged T14-style, 1 barrier/stage.
// Bias/fin_w table cached in LDS (1KB) to keep acc-init off the VMEM path.

__device__ __forceinline__ void bias_init32(f32x16 acc[2], const float* bp) {
#pragma unroll
    for (int mo = 0; mo < 2; ++mo)
#pragma unroll
        for (int q = 0; q < 4; ++q) {
            float4 b = *(const float4*)(bp + (mo * 4 + q) * 8);
            acc[mo][4 * q + 0] = b.x;
            acc[mo][4 * q + 1] = b.y;
            acc[mo][4 * q + 2] = b.z;
            acc[mo][4 * q + 3] = b.w;
        }
}

// relu + split + native transpose via permlane32_swap.
__device__ __forceinline__ void exchange32(const f32x16 acc[2], unsigned BH[4][4], unsigned BL[4][4]) {
#pragma unroll
    for (int kts = 0; kts < 4; ++kts) {
        const int mo = kts >> 1;
        const int base = 8 * (kts & 1);
        float r0 = fmaxf(acc[mo][base + 0], 0.f), r1 = fmaxf(acc[mo][base + 1], 0.f);
        float r2 = fmaxf(acc[mo][base + 2], 0.f), r3 = fmaxf(acc[mo][base + 3], 0.f);
        float r4 = fmaxf(acc[mo][base + 4], 0.f), r5 = fmaxf(acc[mo][base + 5], 0.f);
        float r6 = fmaxf(acc[mo][base + 6], 0.f), r7 = fmaxf(acc[mo][base + 7], 0.f);
        unsigned pA0, pA1, pB0, pB1;
        asm("v_cvt_pk_bf16_f32 %0, %1, %2" : "=v"(pA0) : "v"(r0), "v"(r1));
        asm("v_cvt_pk_bf16_f32 %0, %1, %2" : "=v"(pA1) : "v"(r2), "v"(r3));
        asm("v_cvt_pk_bf16_f32 %0, %1, %2" : "=v"(pB0) : "v"(r4), "v"(r5));
        asm("v_cvt_pk_bf16_f32 %0, %1, %2" : "=v"(pB1) : "v"(r6), "v"(r7));
        float d0 = r0 - __uint_as_float(pA0 << 16);
        float d1 = r1 - __uint_as_float(pA0 & 0xFFFF0000u);
        float d2 = r2 - __uint_as_float(pA1 << 16);
        float d3 = r3 - __uint_as_float(pA1 & 0xFFFF0000u);
        float d4 = r4 - __uint_as_float(pB0 << 16);
        float d5 = r5 - __uint_as_float(pB0 & 0xFFFF0000u);
        float d6 = r6 - __uint_as_float(pB1 << 16);
        float d7 = r7 - __uint_as_float(pB1 & 0xFFFF0000u);
        unsigned qA0, qA1, qB0, qB1;
        asm("v_cvt_pk_bf16_f32 %0, %1, %2" : "=v"(qA0) : "v"(d0), "v"(d1));
        asm("v_cvt_pk_bf16_f32 %0, %1, %2" : "=v"(qA1) : "v"(d2), "v"(d3));
        asm("v_cvt_pk_bf16_f32 %0, %1, %2" : "=v"(qB0) : "v"(d4), "v"(d5));
        asm("v_cvt_pk_bf16_f32 %0, %1, %2" : "=v"(qB1) : "v"(d6), "v"(d7));
        uint2v sw0 = __builtin_amdgcn_permlane32_swap(pA0, pB0, false, false);
        uint2v sw1 = __builtin_amdgcn_permlane32_swap(pA1, pB1, false, false);
        BH[kts][0] = sw0[0]; BH[kts][1] = sw1[0]; BH[kts][2] = sw0[1]; BH[kts][3] = sw1[1];
        uint2v tw0 = __builtin_amdgcn_permlane32_swap(qA0, qB0, false, false);
        uint2v tw1 = __builtin_amdgcn_permlane32_swap(qA1, qB1, false, false);
        BL[kts][0] = tw0[0]; BL[kts][1] = tw1[0]; BL[kts][2] = tw0[1]; BL[kts][3] = tw1[1];
    }
}

__device__ __forceinline__ void loadB32(const unsigned short* xhi, const unsigned short* xlo,
                                        int node, int l5, unsigned BH[4][4], unsigned BL[4][4]) {
    const uint4* hp = (const uint4*)xhi + (size_t)node * 8;
    const uint4* lp = (const uint4*)xlo + (size_t)node * 8;
#pragma unroll
    for (int kts = 0; kts < 4; ++kts) {
        uint4 h = hp[2 * kts + l5];
        BH[kts][0] = h.x; BH[kts][1] = h.y; BH[kts][2] = h.z; BH[kts][3] = h.w;
        uint4 l = lp[2 * kts + l5];
        BL[kts][0] = l.x; BL[kts][1] = l.y; BL[kts][2] = l.z; BL[kts][3] = l.w;
    }
}

template <int KTS>
__device__ __forceinline__ void mfma32(f32x16 acc[2], const uint4* wl,
                                       const unsigned BH[4][4], const unsigned BL[4][4], int lane) {
#pragma unroll
    for (int kt = 0; kt < KTS; ++kt) {
        short8v Bh = as_frag(make_uint4(BH[kt][0], BH[kt][1], BH[kt][2], BH[kt][3]));
        short8v Bl = as_frag(make_uint4(BL[kt][0], BL[kt][1], BL[kt][2], BL[kt][3]));
#pragma unroll
        for (int mo = 0; mo < 2; ++mo) {
            short8v Ah = as_frag(wl[((mo * 4 + kt) * 2 + 0) * 64 + lane]);
            short8v Al = as_frag(wl[((mo * 4 + kt) * 2 + 1) * 64 + lane]);
            acc[mo] = __builtin_amdgcn_mfma_f32_32x32x16_bf16(Ah, Bh, acc[mo], 0, 0, 0);
            acc[mo] = __builtin_amdgcn_mfma_f32_32x32x16_bf16(Al, Bh, acc[mo], 0, 0, 0);
            acc[mo] = __builtin_amdgcn_mfma_f32_32x32x16_bf16(Ah, Bl, acc[mo], 0, 0, 0);
        }
    }
}

__global__ __launch_bounds__(256, 4) void k_mega(
    const float* __restrict__ ea, const int* __restrict__ src, const int* __restrict__ dst,
    const unsigned short* __restrict__ xhi, const unsigned short* __restrict__ xlo,
    const unsigned* __restrict__ wpk, const float* __restrict__ bias3,
    float* __restrict__ out) {
    __shared__ uint4 wlds[2][1024];   // 2 x 16 KB weight double-buffer
    __shared__ float blds[1024];      // bias / fin_w table (1 KB used región)
    const int tid = threadIdx.x;
    const int wv = tid >> 6, lane = tid & 63;
    const int l5 = lane >> 5, n = lane & 31;
    const int e = blockIdx.x * 128 + wv * 32 + n;
    const uint4* wpk4 = (const uint4*)wpk;

    // prologue: stage-0 weights + bias table into LDS
#pragma unroll
    for (int j = 0; j < 4; ++j) wlds[0][tid + 256 * j] = wpk4[tid + 256 * j];
#pragma unroll
    for (int j = 0; j < 4; ++j) blds[tid + 256 * j] = bias3[tid + 256 * j];

    // edge node indices (hoisted)
    const int nsrc = src[e];
    const int ndst = dst[e];

    f32x16 acc[2];
    unsigned BH[4][4], BL[4][4];

    // s0 B-frags from edge_attr (K=16, slice 0 only)
    {
        const float4* ar = (const float4*)(ea + (size_t)e * 16 + 8 * l5);
        float4 f0 = ar[0], f1 = ar[1];
        float xv[8] = {f0.x, f0.y, f0.z, f0.w, f1.x, f1.y, f1.z, f1.w};
        uint4 hf, lf;
        split_pack8(xv, hf, lf);
        BH[0][0] = hf.x; BH[0][1] = hf.y; BH[0][2] = hf.z; BH[0][3] = hf.w;
        BL[0][0] = lf.x; BL[0][1] = lf.y; BL[0][2] = lf.z; BL[0][3] = lf.w;
    }
    __syncthreads();

    for (int s = 0; s < 14; ++s) {
        uint4 st0, st1, st2, st3;
        if (s < 13) {   // issue next-stage weight loads early (T14)
            const uint4* np = wpk4 + (size_t)(s + 1) * 1024;
            st0 = np[tid]; st1 = np[tid + 256]; st2 = np[tid + 512]; st3 = np[tid + 768];
        }
        const uint4* wl = wlds[s & 1];
        if (s == 0) {
            bias_init32(acc, blds + l5 * 4);
            mfma32<1>(acc, wl, BH, BL, lane);
        } else if (s == 9 || s == 10) {
            loadB32(xhi, xlo, (s == 9) ? nsrc : ndst, l5, BH, BL);
            mfma32<4>(acc, wl, BH, BL, lane);     // accumulate into out-MLP acc
        } else {
            exchange32(acc, BH, BL);
            bias_init32(acc, blds + s * 64 + l5 * 4);
            mfma32<4>(acc, wl, BH, BL, lane);
        }
        if (s < 13) {   // write-late into the other buffer
            uint4* nb = wlds[(s + 1) & 1];
            nb[tid] = st0; nb[tid + 256] = st1; nb[tid + 512] = st2; nb[tid + 768] = st3;
        }
        __syncthreads();
    }

    // final dot: out = relu(P14)^T . fin_w + fin_b
    float v = 0.f;
#pragma unroll
    for (int mo = 0; mo < 2; ++mo)
#pragma unroll
        for (int q = 0; q < 4; ++q) {
            float4 w4 = *(const float4*)(blds + 14 * 64 + (mo * 4 + q) * 8 + l5 * 4);
            v = fmaf(fmaxf(acc[mo][4 * q + 0], 0.f), w4.x, v);
            v = fmaf(fmaxf(acc[mo][4 * q + 1], 0.f), w4.y, v);
            v = fmaf(fmaxf(acc[mo][4 * q + 2], 0.f), w4.z, v);
            v = fmaf(fmaxf(acc[mo][4 * q + 3], 0.f), w4.w, v);
        }
    v += __shfl_xor(v, 32, 64);
    if (lane < 32) out[e] = v + blds[15 * 64];
}

// ---------------- launch ----------------

extern "C" void kernel_launch(void* const* d_in, const int* in_sizes, int n_in,
                              void* d_out, int out_size, void* d_ws, size_t ws_size,
                              hipStream_t stream) {
    (void)in_sizes; (void)n_in; (void)out_size; (void)ws_size;

    const float* x         = (const float*)d_in[0];
    const int*   src       = (const int*)d_in[1];
    const int*   dst       = (const int*)d_in[2];
    const float* edge_attr = (const float*)d_in[3];
    const float* gcn_w     = (const float*)d_in[4];
    const float* gcn_b     = (const float*)d_in[5];
    const float* edge_w0   = (const float*)d_in[6];
    const float* edge_b0   = (const float*)d_in[7];
    const float* edge_w    = (const float*)d_in[8];
    const float* edge_b    = (const float*)d_in[9];
    const float* out_w0    = (const float*)d_in[10];
    const float* out_b0    = (const float*)d_in[11];
    const float* out_w     = (const float*)d_in[12];
    const float* out_b     = (const float*)d_in[13];
    const float* fin_w     = (const float*)d_in[14];
    const float* fin_b     = (const float*)d_in[15];
    float* out = (float*)d_out;

    float* ws    = (float*)d_ws;
    float* dinv  = ws;                                  // NPAD
    float* xbufA = dinv + NPAD;                         // N*64
    float* xl    = xbufA + N_NODES * 64;                // N*64
    unsigned short* xhi = (unsigned short*)(xl + N_NODES * 64);   // N*64 u16
    unsigned short* xlo = xhi + N_NODES * 64;                     // N*64 u16
    float* scr   = (float*)(xlo + N_NODES * 64);
    unsigned* wpk   = (unsigned*)scr;                   // 18*4096 = 73728 u32
    float* bias3    = scr + 73728;                      // 1024 padded
    int* degi       = (int*)(scr + 74816);              // NPAD
    int* cur        = degi + NPAD;                      // NPAD (adjacent for one memset)
    int* part       = cur + NPAD;                       // NPAD
    int* bsum       = part + NPAD;                      // 256
    int* rowp       = bsum + 256;                       // NPAD
    int* es         = rowp + NPAD;                      // E
    float* en       = (float*)(es + N_EDGES);           // E

    const int EB = N_EDGES / 256;                       // 3125
    const int NB = NPAD / 256;                          // 196

    hipMemsetAsync(degi, 0, 2 * NPAD * sizeof(int), stream);
    k_deg_i<<<EB, 256, 0, stream>>>(dst, degi);
    k_scan1<<<NB, 256, 0, stream>>>(degi, part, bsum, dinv);
    k_scan2<<<1, 256, 0, stream>>>(bsum);
    k_scan3<<<NB, 256, 0, stream>>>(part, bsum, rowp);
    k_place<<<EB, 256, 0, stream>>>(src, dst, dinv, rowp, cur, es, en);

    k_wprep<<<36, 256, 0, stream>>>(edge_w0, edge_w, out_w0, out_w, gcn_w, wpk);
    k_bprep<<<4, 256, 0, stream>>>(edge_b0, edge_b, out_b0, out_b, fin_w, fin_b, bias3);

    const float* xin = x;
    for (int layer = 0; layer < 4; ++layer) {
        k_xlm<<<(NPAD / 128), 256, 0, stream>>>(xin, wpk, 14 + layer, xl);
        k_agg<<<(N_NODES + 3) / 4, 256, 0, stream>>>(xl, es, en, rowp, dinv,
                                                     gcn_b + layer * 64, xbufA,
                                                     xhi, xlo, (layer == 3) ? 1 : 0);
        xin = xbufA;
    }

    k_mega<<<N_EDGES / 128, 256, 0, stream>>>(edge_attr, src, dst, xhi, xlo,
                                              wpk, bias3, out);
}

// Round 8
// 489.961 us; speedup vs baseline: 1.7519x; 1.1947x over previous
//
#include <hip/hip_runtime.h>
#include <hip/hip_fp16.h>

#define N_NODES 50000
#define N_EDGES 800000
#define NPAD 50176   // 196*256

typedef __attribute__((ext_vector_type(8))) short short8v;   // 8 bf16 (4 VGPR)
typedef __attribute__((ext_vector_type(4))) float f32x4;
typedef __attribute__((ext_vector_type(16))) float f32x16;
typedef __attribute__((ext_vector_type(2))) unsigned uint2v;

union U4S8 { uint4 u; short8v s; };
__device__ __forceinline__ short8v as_frag(uint4 u) { U4S8 t; t.u = u; return t.s; }
__device__ __forceinline__ uint4 zero4() { return make_uint4(0u, 0u, 0u, 0u); }

// direct global->LDS 16B copy (linear both sides)
__device__ __forceinline__ void gload_lds16(const uint4* g, uint4* l) {
    __builtin_amdgcn_global_load_lds((const __attribute__((address_space(1))) void*)g,
                                     (__attribute__((address_space(3))) void*)l, 16, 0, 0);
}

// ---------------- degree / CSR build ----------------

__global__ __launch_bounds__(256) void k_deg_i(const int* __restrict__ dst, int* __restrict__ degi) {
    int e = blockIdx.x * 256 + threadIdx.x;
    if (e < N_EDGES) atomicAdd(&degi[dst[e]], 1);
}

__global__ __launch_bounds__(256) void k_scan1(const int* __restrict__ degi, int* __restrict__ part,
                                               int* __restrict__ bsum, float* __restrict__ dinv) {
    __shared__ int tmp[256];
    int t = threadIdx.x, gid = blockIdx.x * 256 + t;
    int v = degi[gid];
    if (gid < N_NODES) dinv[gid] = rsqrtf((float)v + 1.0f);
    tmp[t] = v;
    __syncthreads();
    for (int off = 1; off < 256; off <<= 1) {
        int add = (t >= off) ? tmp[t - off] : 0;
        __syncthreads();
        tmp[t] += add;
        __syncthreads();
    }
    part[gid] = tmp[t] - v;
    if (t == 255) bsum[blockIdx.x] = tmp[t];
}

__global__ __launch_bounds__(256) void k_scan2(int* __restrict__ bsum) {
    __shared__ int tmp[256];
    int t = threadIdx.x;
    int v = (t < 196) ? bsum[t] : 0;
    tmp[t] = v;
    __syncthreads();
    for (int off = 1; off < 256; off <<= 1) {
        int add = (t >= off) ? tmp[t - off] : 0;
        __syncthreads();
        tmp[t] += add;
        __syncthreads();
    }
    if (t < 196) bsum[t] = tmp[t] - v;
}

__global__ __launch_bounds__(256) void k_scan3(const int* __restrict__ part, const int* __restrict__ bsum,
                                               int* __restrict__ rowp) {
    int gid = blockIdx.x * 256 + threadIdx.x;
    rowp[gid] = part[gid] + bsum[blockIdx.x];
}

__global__ __launch_bounds__(256) void k_place(const int* __restrict__ src, const int* __restrict__ dst,
                                               const float* __restrict__ dinv, const int* __restrict__ rowp,
                                               int* __restrict__ cur, int* __restrict__ es, float* __restrict__ en) {
    int e = blockIdx.x * 256 + threadIdx.x;
    if (e >= N_EDGES) return;
    int s = src[e], d = dst[e];
    int p = atomicAdd(&cur[d], 1);
    int slot = rowp[d] + p;
    es[slot] = s;
    en[slot] = dinv[s] * dinv[d];
}

// ---------------- weight / bias pre-pack (unchanged layouts) ----------------

__global__ __launch_bounds__(256) void k_wprep(const float* __restrict__ ew0, const float* __restrict__ ew,
                                               const float* __restrict__ ow0, const float* __restrict__ ow,
                                               const float* __restrict__ gw, unsigned* __restrict__ wpk) {
    int t = blockIdx.x * 256 + threadIdx.x;
    if (t >= 18 * 512) return;
    int lane = t & 63;
    int s = t >> 9;
    unsigned hu[8], lu[8];
    if (s < 14) {
        int q = (t >> 6) & 7;
        int mo = q >> 2, kts = q & 3;
        int fo = 32 * mo + (lane & 31);
#pragma unroll
        for (int i = 0; i < 8; ++i) {
            int fi = 16 * kts + 8 * (lane >> 5) + i;
            float w = 0.f;
            if (s == 0)       { if (fi < 16) w = ew0[fi * 64 + fo]; }
            else if (s <= 7)  w = ew[((s - 1) * 64 + fi) * 64 + fo];
            else if (s == 8)  w = ow0[(128 + fi) * 64 + fo];
            else if (s == 9)  w = ow0[fi * 64 + fo];
            else if (s == 10) w = ow0[(64 + fi) * 64 + fo];
            else              w = ow[((s - 11) * 64 + fi) * 64 + fo];
            unsigned u = __float_as_uint(w);
            unsigned h = u & 0xFFFF0000u;
            float d = w - __uint_as_float(h);
            hu[i] = h >> 16;
            lu[i] = __float_as_uint(d) >> 16;
        }
        uint4* o = (uint4*)wpk + (size_t)s * 1024 + (q * 2) * 64 + lane;
        o[0]  = make_uint4(hu[0] | (hu[1] << 16), hu[2] | (hu[3] << 16), hu[4] | (hu[5] << 16), hu[6] | (hu[7] << 16));
        o[64] = make_uint4(lu[0] | (lu[1] << 16), lu[2] | (lu[3] << 16), lu[4] | (lu[5] << 16), lu[6] | (lu[7] << 16));
    } else {
        int nt = (t >> 6) & 3;
        int kt = (t >> 8) & 1;
        int n = nt * 16 + (lane & 15);
#pragma unroll
        for (int i = 0; i < 8; ++i) {
            int k = kt * 32 + ((lane >> 4) * 8) + i;
            float w = gw[((s - 14) * 64 + k) * 64 + n];
            unsigned u = __float_as_uint(w);
            unsigned h = u & 0xFFFF0000u;
            float d = w - __uint_as_float(h);
            hu[i] = h >> 16;
            lu[i] = __float_as_uint(d) >> 16;
        }
        uint4* o = (uint4*)(wpk + (size_t)t * 8);
        o[0] = make_uint4(hu[0] | (hu[1] << 16), hu[2] | (hu[3] << 16), hu[4] | (hu[5] << 16), hu[6] | (hu[7] << 16));
        o[1] = make_uint4(lu[0] | (lu[1] << 16), lu[2] | (lu[3] << 16), lu[4] | (lu[5] << 16), lu[6] | (lu[7] << 16));
    }
}

__global__ __launch_bounds__(256) void k_bprep(const float* __restrict__ eb0, const float* __restrict__ eb,
                                               const float* __restrict__ ob0, const float* __restrict__ ob,
                                               const float* __restrict__ finw, const float* __restrict__ finb,
                                               float* __restrict__ bias3) {
    int t = blockIdx.x * 256 + threadIdx.x;
    if (t >= 1024) return;
    if (t == 15 * 64) { bias3[t] = finb[0]; return; }
    if (t > 15 * 64)  { bias3[t] = 0.f; return; }
    int s = t >> 6, idx = t & 63;
    int j = idx & 3, l5 = (idx >> 2) & 1, q = (idx >> 3) & 3, mo = idx >> 5;
    int f = 32 * mo + 8 * q + 4 * l5 + j;
    float b = 0.f;
    if (s == 0) b = eb0[f];
    else if (s <= 7) b = eb[(s - 1) * 64 + f];
    else if (s == 8) b = ob0[f];
    else if (s >= 11 && s <= 13) b = ob[(s - 11) * 64 + f];
    else if (s == 14) b = finw[f];
    bias3[t] = b;
}

// ---------------- shared split helpers ----------------

__device__ __forceinline__ void split_pack8(const float* xv, uint4& hfrag, uint4& lfrag) {
    unsigned hu[8], lu[8];
#pragma unroll
    for (int i = 0; i < 8; ++i) {
        unsigned u = __float_as_uint(xv[i]);
        unsigned h = u & 0xFFFF0000u;
        float d = xv[i] - __uint_as_float(h);
        hu[i] = h >> 16;
        lu[i] = __float_as_uint(d) >> 16;
    }
    hfrag = make_uint4(hu[0] | (hu[1] << 16), hu[2] | (hu[3] << 16), hu[4] | (hu[5] << 16), hu[6] | (hu[7] << 16));
    lfrag = make_uint4(lu[0] | (lu[1] << 16), lu[2] | (lu[3] << 16), lu[4] | (lu[5] << 16), lu[6] | (lu[7] << 16));
}

__device__ __forceinline__ void load_a_global_kt(const float* rowp, int kt, int g, uint4& aH, uint4& aL) {
    const float4* r4 = (const float4*)(rowp + kt * 32 + g * 8);
    float4 f0 = r4[0], f1 = r4[1];
    float xv[8] = {f0.x, f0.y, f0.z, f0.w, f1.x, f1.y, f1.z, f1.w};
    split_pack8(xv, aH, aL);
}

// 16x16x32 B-operand mfma (gcn node GEMM only)
__device__ __forceinline__ void mfma_stage(f32x4 acc[2][4], const uint4* wqs,
                                           const uint4 aH[2][2], const uint4 aL[2][2], int lane) {
#pragma unroll
    for (int kt = 0; kt < 2; ++kt) {
#pragma unroll
        for (int nt = 0; nt < 4; ++nt) {
            const uint4* wq = wqs + ((size_t)((kt * 4 + nt) * 64 + lane)) * 2;
            short8v bh = as_frag(wq[0]);
            short8v bl = as_frag(wq[1]);
#pragma unroll
            for (int mt = 0; mt < 2; ++mt) {
                short8v ah = as_frag(aH[mt][kt]);
                short8v al = as_frag(aL[mt][kt]);
                acc[mt][nt] = __builtin_amdgcn_mfma_f32_16x16x32_bf16(ah, bh, acc[mt][nt], 0, 0, 0);
                acc[mt][nt] = __builtin_amdgcn_mfma_f32_16x16x32_bf16(al, bh, acc[mt][nt], 0, 0, 0);
                acc[mt][nt] = __builtin_amdgcn_mfma_f32_16x16x32_bf16(ah, bl, acc[mt][nt], 0, 0, 0);
            }
        }
    }
}

// ---------------- GCN node GEMM: writes xl as f16 ----------------

__global__ __launch_bounds__(256, 3) void k_xlm(const float* __restrict__ xin,
                                                const unsigned* __restrict__ wpk, int stage,
                                                __half* __restrict__ xlh) {
    const int tid = threadIdx.x;
    const int wv = tid >> 6, lane = tid & 63;
    const int g = lane >> 4, l15 = lane & 15;
    const int rb = blockIdx.x * 128 + wv * 32;
    const uint4* wq = (const uint4*)wpk + (size_t)stage * 1024;

    f32x4 acc[2][4];
    uint4 aH[2][2], aL[2][2];
#pragma unroll
    for (int mt = 0; mt < 2; ++mt) {
        int row = rb + mt * 16 + l15;
        if (row < N_NODES) {
            const float* rowp = xin + (size_t)row * 64;
#pragma unroll
            for (int kt = 0; kt < 2; ++kt) load_a_global_kt(rowp, kt, g, aH[mt][kt], aL[mt][kt]);
        } else {
#pragma unroll
            for (int kt = 0; kt < 2; ++kt) { aH[mt][kt] = zero4(); aL[mt][kt] = zero4(); }
        }
#pragma unroll
        for (int nt = 0; nt < 4; ++nt) acc[mt][nt] = (f32x4){0.f, 0.f, 0.f, 0.f};
    }
    mfma_stage(acc, wq, aH, aL, lane);
#pragma unroll
    for (int mt = 0; mt < 2; ++mt)
#pragma unroll
        for (int nt = 0; nt < 4; ++nt)
#pragma unroll
            for (int r = 0; r < 4; ++r) {
                int row = rb + mt * 16 + g * 4 + r;
                if (row < N_NODES) xlh[(size_t)row * 64 + nt * 16 + l15] = __float2half(acc[mt][nt][r]);
            }
}

// ---------------- segmented aggregation: f16 gathers, shfl-broadcast es/en ----------------

__global__ __launch_bounds__(256) void k_agg(const __half* __restrict__ xlh,
                                             const int* __restrict__ es, const float* __restrict__ en,
                                             const int* __restrict__ rowp, const float* __restrict__ dinv,
                                             const float* __restrict__ b, float* __restrict__ xout,
                                             unsigned short* __restrict__ oh, unsigned short* __restrict__ ol,
                                             int writeSplit) {
    int n = blockIdx.x * 4 + (threadIdx.x >> 6);
    int j = threadIdx.x & 63;
    if (n >= N_NODES) return;
    const int i0 = rowp[n], e1 = rowp[n + 1];
    float a0 = 0.f, a1 = 0.f, a2 = 0.f, a3 = 0.f;
    for (int base = i0; base < e1; base += 64) {
        int cnt = e1 - base;
        if (cnt > 64) cnt = 64;
        int se = 0;
        float we = 0.f;
        if (base + j < e1) { se = es[base + j]; we = en[base + j]; }
        int k = 0;
        for (; k + 4 <= cnt; k += 4) {
            int s0 = __shfl(se, k + 0); float w0 = __shfl(we, k + 0);
            int s1 = __shfl(se, k + 1); float w1 = __shfl(we, k + 1);
            int s2 = __shfl(se, k + 2); float w2 = __shfl(we, k + 2);
            int s3 = __shfl(se, k + 3); float w3 = __shfl(we, k + 3);
            a0 = fmaf(w0, __half2float(xlh[(size_t)s0 * 64 + j]), a0);
            a1 = fmaf(w1, __half2float(xlh[(size_t)s1 * 64 + j]), a1);
            a2 = fmaf(w2, __half2float(xlh[(size_t)s2 * 64 + j]), a2);
            a3 = fmaf(w3, __half2float(xlh[(size_t)s3 * 64 + j]), a3);
        }
        for (; k < cnt; ++k) {
            int s0 = __shfl(se, k); float w0 = __shfl(we, k);
            a0 = fmaf(w0, __half2float(xlh[(size_t)s0 * 64 + j]), a0);
        }
    }
    float di = dinv[n];
    float val = (a0 + a1) + (a2 + a3) + di * di * __half2float(xlh[(size_t)n * 64 + j]) + b[j];
    float v = fmaxf(val, 0.f);
    size_t idx = (size_t)n * 64 + j;
    xout[idx] = v;
    if (writeSplit) {
        unsigned u = __float_as_uint(v);
        oh[idx] = (unsigned short)(u >> 16);
        float d = v - __uint_as_float(u & 0xFFFF0000u);
        ol[idx] = (unsigned short)(__float_as_uint(d) >> 16);
    }
}

// ---------------- fused edge mega kernel: 32x32x16 + permlane32_swap + gload_lds ----------------

__device__ __forceinline__ void bias_init32(f32x16 acc[2], const float* bp) {
#pragma unroll
    for (int mo = 0; mo < 2; ++mo)
#pragma unroll
        for (int q = 0; q < 4; ++q) {
            float4 b = *(const float4*)(bp + (mo * 4 + q) * 8);
            acc[mo][4 * q + 0] = b.x;
            acc[mo][4 * q + 1] = b.y;
            acc[mo][4 * q + 2] = b.z;
            acc[mo][4 * q + 3] = b.w;
        }
}

// relu + split + native transpose via permlane32_swap.
__device__ __forceinline__ void exchange32(const f32x16 acc[2], unsigned BH[4][4], unsigned BL[4][4]) {
#pragma unroll
    for (int kts = 0; kts < 4; ++kts) {
        const int mo = kts >> 1;
        const int base = 8 * (kts & 1);
        float r0 = fmaxf(acc[mo][base + 0], 0.f), r1 = fmaxf(acc[mo][base + 1], 0.f);
        float r2 = fmaxf(acc[mo][base + 2], 0.f), r3 = fmaxf(acc[mo][base + 3], 0.f);
        float r4 = fmaxf(acc[mo][base + 4], 0.f), r5 = fmaxf(acc[mo][base + 5], 0.f);
        float r6 = fmaxf(acc[mo][base + 6], 0.f), r7 = fmaxf(acc[mo][base + 7], 0.f);
        unsigned pA0, pA1, pB0, pB1;
        asm("v_cvt_pk_bf16_f32 %0, %1, %2" : "=v"(pA0) : "v"(r0), "v"(r1));
        asm("v_cvt_pk_bf16_f32 %0, %1, %2" : "=v"(pA1) : "v"(r2), "v"(r3));
        asm("v_cvt_pk_bf16_f32 %0, %1, %2" : "=v"(pB0) : "v"(r4), "v"(r5));
        asm("v_cvt_pk_bf16_f32 %0, %1, %2" : "=v"(pB1) : "v"(r6), "v"(r7));
        float d0 = r0 - __uint_as_float(pA0 << 16);
        float d1 = r1 - __uint_as_float(pA0 & 0xFFFF0000u);
        float d2 = r2 - __uint_as_float(pA1 << 16);
        float d3 = r3 - __uint_as_float(pA1 & 0xFFFF0000u);
        float d4 = r4 - __uint_as_float(pB0 << 16);
        float d5 = r5 - __uint_as_float(pB0 & 0xFFFF0000u);
        float d6 = r6 - __uint_as_float(pB1 << 16);
        float d7 = r7 - __uint_as_float(pB1 & 0xFFFF0000u);
        unsigned qA0, qA1, qB0, qB1;
        asm("v_cvt_pk_bf16_f32 %0, %1, %2" : "=v"(qA0) : "v"(d0), "v"(d1));
        asm("v_cvt_pk_bf16_f32 %0, %1, %2" : "=v"(qA1) : "v"(d2), "v"(d3));
        asm("v_cvt_pk_bf16_f32 %0, %1, %2" : "=v"(qB0) : "v"(d4), "v"(d5));
        asm("v_cvt_pk_bf16_f32 %0, %1, %2" : "=v"(qB1) : "v"(d6), "v"(d7));
        uint2v sw0 = __builtin_amdgcn_permlane32_swap(pA0, pB0, false, false);
        uint2v sw1 = __builtin_amdgcn_permlane32_swap(pA1, pB1, false, false);
        BH[kts][0] = sw0[0]; BH[kts][1] = sw1[0]; BH[kts][2] = sw0[1]; BH[kts][3] = sw1[1];
        uint2v tw0 = __builtin_amdgcn_permlane32_swap(qA0, qB0, false, false);
        uint2v tw1 = __builtin_amdgcn_permlane32_swap(qA1, qB1, false, false);
        BL[kts][0] = tw0[0]; BL[kts][1] = tw1[0]; BL[kts][2] = tw0[1]; BL[kts][3] = tw1[1];
    }
}

__device__ __forceinline__ void loadB32(const unsigned short* xhi, const unsigned short* xlo,
                                        int node, int l5, unsigned BH[4][4], unsigned BL[4][4]) {
    const uint4* hp = (const uint4*)xhi + (size_t)node * 8;
    const uint4* lp = (const uint4*)xlo + (size_t)node * 8;
#pragma unroll
    for (int kts = 0; kts < 4; ++kts) {
        uint4 h = hp[2 * kts + l5];
        BH[kts][0] = h.x; BH[kts][1] = h.y; BH[kts][2] = h.z; BH[kts][3] = h.w;
        uint4 l = lp[2 * kts + l5];
        BL[kts][0] = l.x; BL[kts][1] = l.y; BL[kts][2] = l.z; BL[kts][3] = l.w;
    }
}

template <int KTS>
__device__ __forceinline__ void mfma32(f32x16 acc[2], const uint4* wl,
                                       const unsigned BH[4][4], const unsigned BL[4][4], int lane) {
#pragma unroll
    for (int kt = 0; kt < KTS; ++kt) {
        short8v Bh = as_frag(make_uint4(BH[kt][0], BH[kt][1], BH[kt][2], BH[kt][3]));
        short8v Bl = as_frag(make_uint4(BL[kt][0], BL[kt][1], BL[kt][2], BL[kt][3]));
#pragma unroll
        for (int mo = 0; mo < 2; ++mo) {
            short8v Ah = as_frag(wl[((mo * 4 + kt) * 2 + 0) * 64 + lane]);
            short8v Al = as_frag(wl[((mo * 4 + kt) * 2 + 1) * 64 + lane]);
            acc[mo] = __builtin_amdgcn_mfma_f32_32x32x16_bf16(Ah, Bh, acc[mo], 0, 0, 0);
            acc[mo] = __builtin_amdgcn_mfma_f32_32x32x16_bf16(Al, Bh, acc[mo], 0, 0, 0);
            acc[mo] = __builtin_amdgcn_mfma_f32_32x32x16_bf16(Ah, Bl, acc[mo], 0, 0, 0);
        }
    }
}

__global__ __launch_bounds__(256, 4) void k_mega(
    const float* __restrict__ ea, const int* __restrict__ src, const int* __restrict__ dst,
    const unsigned short* __restrict__ xhi, const unsigned short* __restrict__ xlo,
    const unsigned* __restrict__ wpk, const float* __restrict__ bias3,
    float* __restrict__ out) {
    __shared__ uint4 wlds[2][1024];   // 2 x 16 KB weight double-buffer
    __shared__ float blds[1024];      // bias / fin_w table
    const int tid = threadIdx.x;
    const int wv = tid >> 6, lane = tid & 63;
    const int l5 = lane >> 5, n = lane & 31;
    const int e = blockIdx.x * 128 + wv * 32 + n;
    const uint4* wpk4 = (const uint4*)wpk;

    // prologue: stage-0 weights (direct to LDS) + bias table
#pragma unroll
    for (int j = 0; j < 4; ++j) gload_lds16(wpk4 + tid + 256 * j, &wlds[0][tid + 256 * j]);
#pragma unroll
    for (int j = 0; j < 4; ++j) blds[tid + 256 * j] = bias3[tid + 256 * j];

    const int nsrc = src[e];
    const int ndst = dst[e];

    f32x16 acc[2];
    unsigned BH[4][4], BL[4][4];

    // s0 B-frags from edge_attr (K=16, slice 0 only)
    {
        const float4* ar = (const float4*)(ea + (size_t)e * 16 + 8 * l5);
        float4 f0 = ar[0], f1 = ar[1];
        float xv[8] = {f0.x, f0.y, f0.z, f0.w, f1.x, f1.y, f1.z, f1.w};
        uint4 hf, lf;
        split_pack8(xv, hf, lf);
        BH[0][0] = hf.x; BH[0][1] = hf.y; BH[0][2] = hf.z; BH[0][3] = hf.w;
        BL[0][0] = lf.x; BL[0][1] = lf.y; BL[0][2] = lf.z; BL[0][3] = lf.w;
    }
    __syncthreads();

    for (int s = 0; s < 14; ++s) {
        if (s < 13) {   // async direct-to-LDS prefetch of next-stage weights
            const uint4* np = wpk4 + (size_t)(s + 1) * 1024;
            uint4* nb = wlds[(s + 1) & 1];
#pragma unroll
            for (int j = 0; j < 4; ++j) gload_lds16(np + tid + 256 * j, &nb[tid + 256 * j]);
        }
        const uint4* wl = wlds[s & 1];
        if (s == 0) {
            bias_init32(acc, blds + l5 * 4);
            mfma32<1>(acc, wl, BH, BL, lane);
        } else if (s == 9 || s == 10) {
            loadB32(xhi, xlo, (s == 9) ? nsrc : ndst, l5, BH, BL);
            mfma32<4>(acc, wl, BH, BL, lane);     // accumulate into out-MLP acc
        } else {
            exchange32(acc, BH, BL);
            bias_init32(acc, blds + s * 64 + l5 * 4);
            mfma32<4>(acc, wl, BH, BL, lane);
        }
        __syncthreads();
    }

    // final dot: out = relu(P14)^T . fin_w + fin_b
    float v = 0.f;
#pragma unroll
    for (int mo = 0; mo < 2; ++mo)
#pragma unroll
        for (int q = 0; q < 4; ++q) {
            float4 w4 = *(const float4*)(blds + 14 * 64 + (mo * 4 + q) * 8 + l5 * 4);
            v = fmaf(fmaxf(acc[mo][4 * q + 0], 0.f), w4.x, v);
            v = fmaf(fmaxf(acc[mo][4 * q + 1], 0.f), w4.y, v);
            v = fmaf(fmaxf(acc[mo][4 * q + 2], 0.f), w4.z, v);
            v = fmaf(fmaxf(acc[mo][4 * q + 3], 0.f), w4.w, v);
        }
    v += __shfl_xor(v, 32, 64);
    if (lane < 32) out[e] = v + blds[15 * 64];
}

// ---------------- launch ----------------

extern "C" void kernel_launch(void* const* d_in, const int* in_sizes, int n_in,
                              void* d_out, int out_size, void* d_ws, size_t ws_size,
                              hipStream_t stream) {
    (void)in_sizes; (void)n_in; (void)out_size; (void)ws_size;

    const float* x         = (const float*)d_in[0];
    const int*   src       = (const int*)d_in[1];
    const int*   dst       = (const int*)d_in[2];
    const float* edge_attr = (const float*)d_in[3];
    const float* gcn_w     = (const float*)d_in[4];
    const float* gcn_b     = (const float*)d_in[5];
    const float* edge_w0   = (const float*)d_in[6];
    const float* edge_b0   = (const float*)d_in[7];
    const float* edge_w    = (const float*)d_in[8];
    const float* edge_b    = (const float*)d_in[9];
    const float* out_w0    = (const float*)d_in[10];
    const float* out_b0    = (const float*)d_in[11];
    const float* out_w     = (const float*)d_in[12];
    const float* out_b     = (const float*)d_in[13];
    const float* fin_w     = (const float*)d_in[14];
    const float* fin_b     = (const float*)d_in[15];
    float* out = (float*)d_out;

    float* ws    = (float*)d_ws;
    float* dinv  = ws;                                  // NPAD
    float* xbufA = dinv + NPAD;                         // N*64 f32
    __half* xlh  = (__half*)(xbufA + N_NODES * 64);     // N*64 f16 (in old xl region)
    unsigned short* xhi = (unsigned short*)((float*)xlh + N_NODES * 64);  // N*64 u16
    unsigned short* xlo = xhi + N_NODES * 64;                             // N*64 u16
    float* scr   = (float*)(xlo + N_NODES * 64);
    unsigned* wpk   = (unsigned*)scr;                   // 18*4096 = 73728 u32
    float* bias3    = scr + 73728;                      // 1024 padded
    int* degi       = (int*)(scr + 74816);              // NPAD
    int* cur        = degi + NPAD;                      // NPAD (adjacent for one memset)
    int* part       = cur + NPAD;                       // NPAD
    int* bsum       = part + NPAD;                      // 256
    int* rowp       = bsum + 256;                       // NPAD
    int* es         = rowp + NPAD;                      // E
    float* en       = (float*)(es + N_EDGES);           // E

    const int EB = N_EDGES / 256;                       // 3125
    const int NB = NPAD / 256;                          // 196

    hipMemsetAsync(degi, 0, 2 * NPAD * sizeof(int), stream);
    k_deg_i<<<EB, 256, 0, stream>>>(dst, degi);
    k_scan1<<<NB, 256, 0, stream>>>(degi, part, bsum, dinv);
    k_scan2<<<1, 256, 0, stream>>>(bsum);
    k_scan3<<<NB, 256, 0, stream>>>(part, bsum, rowp);
    k_place<<<EB, 256, 0, stream>>>(src, dst, dinv, rowp, cur, es, en);

    k_wprep<<<36, 256, 0, stream>>>(edge_w0, edge_w, out_w0, out_w, gcn_w, wpk);
    k_bprep<<<4, 256, 0, stream>>>(edge_b0, edge_b, out_b0, out_b, fin_w, fin_b, bias3);

    const float* xin = x;
    for (int layer = 0; layer < 4; ++layer) {
        k_xlm<<<(NPAD / 128), 256, 0, stream>>>(xin, wpk, 14 + layer, xlh);
        k_agg<<<(N_NODES + 3) / 4, 256, 0, stream>>>(xlh, es, en, rowp, dinv,
                                                     gcn_b + layer * 64, xbufA,
                                                     xhi, xlo, (layer == 3) ? 1 : 0);
        xin = xbufA;
    }

    k_mega<<<N_EDGES / 128, 256, 0, stream>>>(edge_attr, src, dst, xhi, xlo,
                                              wpk, bias3, out);
}